// Round 1
// baseline (832.755 us; speedup 1.0000x reference)
//
#include <hip/hip_runtime.h>
#include <math.h>

#define NN   128
#define TTc  128
#define VVc  25
#define TV   3200
#define BN_EPS 1e-5f

typedef __attribute__((ext_vector_type(8))) short bf8;   // 8 bf16 in 4 VGPRs
typedef __attribute__((ext_vector_type(4))) short s4;    // 4 bf16 (b64)
typedef __attribute__((ext_vector_type(4))) float f4;    // MFMA accumulator

#define MFMA(a,b,c) __builtin_amdgcn_mfma_f32_16x16x32_bf16(a,b,c,0,0,0)

__device__ __forceinline__ float lrelu(float a){ return a>=0.f ? a : 0.1f*a; }
__device__ __forceinline__ short f2bs(float f){
    union{float f; unsigned u;} x; x.f = f;
    unsigned r = x.u + 0x7FFF + ((x.u>>16)&1);
    return (short)(r>>16);
}
__device__ __forceinline__ float b2f(short s){
    union{unsigned u; float f;} x; x.u = ((unsigned)(unsigned short)s)<<16; return x.f;
}
__device__ __forceinline__ s4 packf4(float a,float b,float c,float d){
    s4 r; r.x=f2bs(a); r.y=f2bs(b); r.z=f2bs(c); r.w=f2bs(d); return r;
}

// ---------------------------------------------------------------------------
// Workspace layout (total 178,952,192 B, proven OK):
//  wb bf16 weights       : byte 0
//  attnB bf16 [n][32v][96]: byte 4102144
//  Y  bf16 [n][3200][64] : byte 4888576
//  aT bf16 [n][4][q][t]  : byte 57317376
//  R  : byte 74094592 : XB -> QKT   (phase 3 now fused, no PT buffer)
//  U  : byte 74094592+52428800
// wb element offsets: w_in_s 0 [96][64]; w_out_s 6144 [64][192]; w_ff_s 18432
//  [64][64]; w_in_t 22528 [128][64]; w_out_t 30720 [64][256]; w_ff_t 47104
//  [64][64]; wt 51200 [64][448] (o, dt*64+c)
// ---------------------------------------------------------------------------

__global__ __launch_bounds__(256) void k_prep(
    const float* __restrict__ w_in_s, const float* __restrict__ w_out_s,
    const float* __restrict__ w_ff_s, const float* __restrict__ w_in_t,
    const float* __restrict__ w_out_t, const float* __restrict__ w_ff_t,
    const float* __restrict__ w_tcn, short* __restrict__ wb)
{
    const int total = 51200 + 64*448;
    for (int i = blockIdx.x*256 + threadIdx.x; i < total; i += gridDim.x*256) {
        float v;
        if      (i < 6144)  v = w_in_s[i];
        else if (i < 18432) v = w_out_s[i-6144];
        else if (i < 22528) v = w_ff_s[i-18432];
        else if (i < 30720) v = w_in_t[i-22528];
        else if (i < 47104) v = w_out_t[i-30720];
        else if (i < 51200) v = w_ff_t[i-47104];
        else { int j=i-51200; int o=j/448; int r=j%448; int dt=r>>6; int c=r&63;
               v = w_tcn[(o*64+c)*7 + dt]; }
        wb[i] = f2bs(v);
    }
}

// x f32 [n][c][t][v] -> XB bf16 pixel-major [n][t*25+v][64]
__global__ __launch_bounds__(256) void k_x2b(const float* __restrict__ x, short* __restrict__ XB)
{
    const int n = blockIdx.x >> 4, tc = blockIdx.x & 15, t0 = tc*8;
    const int tid = threadIdx.x;
    __shared__ float xs[64][201];
    const float* xb = x + (size_t)n*204800 + t0*25;
    for (int i = tid; i < 64*200; i += 256) { int c=i/200, p=i%200; xs[c][p] = xb[(size_t)c*3200 + p]; }
    __syncthreads();
    short* ob = XB + (size_t)n*204800 + t0*25*64;
    for (int i = tid; i < 200*64; i += 256) { int p=i>>6, c=i&63; ob[i] = f2bs(xs[c][p]); }
}

// ---------------------------------------------------------------------------
// Fused spatial attention scores (MFMA). grid = N*SS, 4 waves.
// ---------------------------------------------------------------------------
__global__ __launch_bounds__(256) void k_attn_s(
    const short* __restrict__ XB, const short* __restrict__ wb,
    const float* __restrict__ b_in_s, const float* __restrict__ alphas,
    const float* __restrict__ att0s, short* __restrict__ attnB)
{
    const int n = blockIdx.x / 3, s = blockIdx.x % 3;
    const int tid = threadIdx.x, w = tid>>6, lane = tid&63, lr = lane&15, lq = lane>>4;
    __shared__ short ys[208][72];     // staged pixels [px][64c]
    __shared__ short qkl[208][40];    // projected [px][32ch]: 0-15 q, 16-31 k
    __shared__ short wsl[32][72];     // weight rows (q 16 + k 16) x 64c
    __shared__ float bl[32];

    for (int i = tid; i < 32*8; i += 256) {
        const int cl = i>>3, seg = i&7;
        const int row = (cl < 16) ? (s*16 + cl) : (48 + s*16 + (cl-16));
        *(bf8*)&wsl[cl][seg*8] = *(const bf8*)&wb[row*64 + seg*8];
    }
    if (tid < 32) {
        const int row = (tid < 16) ? (s*16 + tid) : (48 + s*16 + (tid-16));
        bl[tid] = b_in_s[row];
    }

    const int mt = w>>1, sn = w&1;     // this wave's score tile (u-tile, v-tile)
    f4 acc = {0.f,0.f,0.f,0.f};

    for (int ch = 0; ch < 16; ++ch) {
        __syncthreads();   // qkl/ys from prev iter fully consumed
        for (int i = tid; i < 208*8; i += 256) {
            const int row = i>>3, seg = i&7;
            bf8 val = {0,0,0,0,0,0,0,0};
            if (row < 200)
                val = *(const bf8*)&XB[((size_t)n*3200 + ch*200 + row)*64 + seg*8];
            *(bf8*)&ys[row][seg*8] = val;
        }
        __syncthreads();
        // projection: wave w covers px-tiles {w, w+4, w+8, w+12}
        for (int nn = 0; nn < 4; ++nn) {
            const int nt2 = w + nn*4;
            if (nt2 >= 13) break;
            const bf8 b0 = *(const bf8*)&ys[nt2*16+lr][lq*8];
            const bf8 b1 = *(const bf8*)&ys[nt2*16+lr][32+lq*8];
            for (int mt2 = 0; mt2 < 2; ++mt2) {
                f4 pa = {0.f,0.f,0.f,0.f};
                const bf8 a0 = *(const bf8*)&wsl[mt2*16+lr][lq*8];
                const bf8 a1 = *(const bf8*)&wsl[mt2*16+lr][32+lq*8];
                pa = MFMA(a0,b0,pa); pa = MFMA(a1,b1,pa);
                const int px = nt2*16+lr, c0 = mt2*16+lq*4;
                *(s4*)&qkl[px][c0] =
                    packf4(pa.x+bl[c0], pa.y+bl[c0+1], pa.z+bl[c0+2], pa.w+bl[c0+3]);
            }
        }
        __syncthreads();
        // score accumulate: k = (t_local, c), 4 steps of 32
        for (int ks = 0; ks < 4; ++ks) {
            const int tl = ks*2 + (lq>>1);
            const bf8 af = *(const bf8*)&qkl[tl*25 + mt*16+lr][(lq&1)*8];
            const bf8 bf = *(const bf8*)&qkl[tl*25 + sn*16+lr][16 + (lq&1)*8];
            acc = MFMA(af, bf, acc);
        }
    }
    const float alpha = alphas[s];
    const int v = sn*16 + lr, u0 = mt*16 + lq*4;
    float r[4];
    #pragma unroll
    for (int j = 0; j < 4; ++j) {
        const int u = u0 + j;
        const float a = (j==0)?acc.x:((j==1)?acc.y:((j==2)?acc.z:acc.w));
        r[j] = (u < 25 && v < 25)
             ? tanhf(a*(1.f/2048.f))*alpha + att0s[s*625 + u*25 + v] : 0.f;
    }
    *(s4*)&attnB[(size_t)n*3072 + v*96 + s*32 + u0] = packf4(r[0],r[1],r[2],r[3]);
}

// ---------------------------------------------------------------------------
// fused spatial block (MFMA). block=(n, t-chunk4), wave w owns t=t0+w.
// ---------------------------------------------------------------------------
__global__ __launch_bounds__(256) void k_spatial(
    const short* __restrict__ XB, const short* __restrict__ attnB, const short* __restrict__ wb,
    const float* __restrict__ b_out, const float* __restrict__ bn_out,
    const float* __restrict__ b_ff,  const float* __restrict__ bn_ff,
    short* __restrict__ Y)
{
    const int n = blockIdx.x >> 5, tc = blockIdx.x & 31, t0 = tc*4;
    const int tid = threadIdx.x;
    const int w = tid>>6, lane = tid&63, lr = lane&15, lq = lane>>4;
    __shared__ short xs[4][32][72];
    __shared__ short wlo[64][200];
    __shared__ short wlf[64][72];
    __shared__ short ab[32][104];
    __shared__ short gsT[4][64][104];
    __shared__ short y1[4][32][72];
    __shared__ float sc1s[64], sh1s[64], sc2s[64], sh2s[64];

    for (int i = tid; i < 4*32*8; i += 256) {
        const int row = i>>3, seg = i&7, tl = row>>5, uv = row&31;
        bf8 val = {0,0,0,0,0,0,0,0};
        if (uv < 25) val = *(const bf8*)&XB[((size_t)n*3200 + (t0+tl)*25 + uv)*64 + seg*8];
        *(bf8*)&xs[tl][uv][seg*8] = val;
    }
    for (int i = tid; i < 64*24; i += 256) {
        const int o = i/24, seg = i%24;
        *(bf8*)&wlo[o][seg*8] = *(const bf8*)&wb[6144 + o*192 + seg*8];
    }
    for (int i = tid; i < 64*8; i += 256) {
        const int o = i>>3, seg = i&7;
        *(bf8*)&wlf[o][seg*8] = *(const bf8*)&wb[18432 + o*64 + seg*8];
    }
    for (int i = tid; i < 32*12; i += 256) {
        const int v = i/12, seg = i%12;
        *(bf8*)&ab[v][seg*8] = *(const bf8*)&attnB[(size_t)n*3072 + v*96 + seg*8];
    }
    if (tid < 64) {
        float g=bn_out[tid], bb=bn_out[64+tid], m=bn_out[128+tid], vv=bn_out[192+tid];
        float inv = g*rsqrtf(vv+BN_EPS);
        sc1s[tid]=inv; sh1s[tid]=(b_out[tid]-m)*inv+bb;
        g=bn_ff[tid]; bb=bn_ff[64+tid]; m=bn_ff[128+tid]; vv=bn_ff[192+tid];
        inv = g*rsqrtf(vv+BN_EPS);
        sc2s[tid]=inv; sh2s[tid]=(b_ff[tid]-m)*inv+bb;
    }
    __syncthreads();

    const int t = t0 + w;
    for (int s = 0; s < 3; ++s) {
        for (int mt = 0; mt < 2; ++mt) {
            const bf8 a0 = *(const bf8*)&xs[w][mt*16+lr][lq*8];
            const bf8 a1 = *(const bf8*)&xs[w][mt*16+lr][32+lq*8];
            for (int nt = 0; nt < 4; ++nt) {
                f4 acc = {0.f,0.f,0.f,0.f};
                const bf8 b0 = *(const bf8*)&wlo[nt*16+lr][s*64 + lq*8];
                const bf8 b1 = *(const bf8*)&wlo[nt*16+lr][s*64 + 32 + lq*8];
                acc = MFMA(a0,b0,acc); acc = MFMA(a1,b1,acc);
                const int o = nt*16+lr, u0 = mt*16+lq*4;
                *(s4*)&gsT[w][o][s*32+u0] = packf4(acc.x,acc.y,acc.z,acc.w);
            }
        }
    }
    for (int mt = 0; mt < 4; ++mt) {
        const bf8 a0 = *(const bf8*)&gsT[w][mt*16+lr][lq*8];
        const bf8 a1 = *(const bf8*)&gsT[w][mt*16+lr][32+lq*8];
        const bf8 a2 = *(const bf8*)&gsT[w][mt*16+lr][64+lq*8];
        for (int nt = 0; nt < 2; ++nt) {
            f4 acc = {0.f,0.f,0.f,0.f};
            const bf8 b0 = *(const bf8*)&ab[nt*16+lr][lq*8];
            const bf8 b1 = *(const bf8*)&ab[nt*16+lr][32+lq*8];
            const bf8 b2 = *(const bf8*)&ab[nt*16+lr][64+lq*8];
            acc = MFMA(a0,b0,acc); acc = MFMA(a1,b1,acc); acc = MFMA(a2,b2,acc);
            const int v = nt*16+lr, o0 = mt*16+lq*4;
            const s4 xr = *(const s4*)&xs[w][v][o0];
            const float r0 = lrelu(acc.x*sc1s[o0  ]+sh1s[o0  ]+b2f(xr.x));
            const float r1 = lrelu(acc.y*sc1s[o0+1]+sh1s[o0+1]+b2f(xr.y));
            const float r2 = lrelu(acc.z*sc1s[o0+2]+sh1s[o0+2]+b2f(xr.z));
            const float r3 = lrelu(acc.w*sc1s[o0+3]+sh1s[o0+3]+b2f(xr.w));
            *(s4*)&y1[w][v][o0] = packf4(r0,r1,r2,r3);
        }
    }
    for (int mt = 0; mt < 4; ++mt) {
        const bf8 a0 = *(const bf8*)&wlf[mt*16+lr][lq*8];
        const bf8 a1 = *(const bf8*)&wlf[mt*16+lr][32+lq*8];
        for (int nt = 0; nt < 2; ++nt) {
            f4 acc = {0.f,0.f,0.f,0.f};
            const bf8 b0 = *(const bf8*)&y1[w][nt*16+lr][lq*8];
            const bf8 b1 = *(const bf8*)&y1[w][nt*16+lr][32+lq*8];
            acc = MFMA(a0,b0,acc); acc = MFMA(a1,b1,acc);
            const int v = nt*16+lr, o0 = mt*16+lq*4;
            if (v < 25) {
                const s4 xr = *(const s4*)&xs[w][v][o0];
                const float r0 = lrelu(acc.x*sc2s[o0  ]+sh2s[o0  ]+b2f(xr.x));
                const float r1 = lrelu(acc.y*sc2s[o0+1]+sh2s[o0+1]+b2f(xr.y));
                const float r2 = lrelu(acc.z*sc2s[o0+2]+sh2s[o0+2]+b2f(xr.z));
                const float r3 = lrelu(acc.w*sc2s[o0+3]+sh2s[o0+3]+b2f(xr.w));
                *(s4*)&Y[((size_t)n*3200 + t*25 + v)*64 + o0] = packf4(r0,r1,r2,r3);
            }
        }
    }
}

// temporal q/k proj -> QKT bf16 [n][t][128oc][25v]
__global__ __launch_bounds__(256) void k_qkt(
    const short* __restrict__ Y, const short* __restrict__ wb,
    const float* __restrict__ b_in_t, short* __restrict__ qkt)
{
    const int n = blockIdx.x >> 5, tc = blockIdx.x & 31, t0 = tc*4;
    const int tid = threadIdx.x;
    const int w = tid>>6, lane = tid&63, lr = lane&15, lq = lane>>4;
    __shared__ short ys[4][32][72];
    __shared__ short wi[128][72];
    for (int i = tid; i < 4*32*8; i += 256) {
        const int row = i>>3, seg = i&7, tl = row>>5, v = row&31;
        bf8 val = {0,0,0,0,0,0,0,0};
        if (v < 25) val = *(const bf8*)&Y[((size_t)n*3200 + (t0+tl)*25 + v)*64 + seg*8];
        *(bf8*)&ys[tl][v][seg*8] = val;
    }
    for (int i = tid; i < 128*8; i += 256) {
        const int o = i>>3, seg = i&7;
        *(bf8*)&wi[o][seg*8] = *(const bf8*)&wb[22528 + o*64 + seg*8];
    }
    __syncthreads();
    for (int mi = 0; mi < 2; ++mi) {
        const int mt = w*2+mi, tl = mt>>1, vh = mt&1;
        const bf8 a0 = *(const bf8*)&ys[tl][vh*16+lr][lq*8];
        const bf8 a1 = *(const bf8*)&ys[tl][vh*16+lr][32+lq*8];
        for (int nt = 0; nt < 8; ++nt) {
            f4 acc = {0.f,0.f,0.f,0.f};
            const bf8 b0 = *(const bf8*)&wi[nt*16+lr][lq*8];
            const bf8 b1 = *(const bf8*)&wi[nt*16+lr][32+lq*8];
            acc = MFMA(a0,b0,acc); acc = MFMA(a1,b1,acc);
            const int oc = nt*16+lr, v0 = vh*16+lq*4, t = t0+tl;
            const float bias = b_in_t[oc];
            const size_t base = (size_t)n*409600 + (size_t)t*3200 + oc*25 + v0;
            if (v0 < 24)
                *(s4*)&qkt[base] = packf4(acc.x+bias, acc.y+bias, acc.z+bias, acc.w+bias);
            else if (v0 == 24)
                qkt[base] = f2bs(acc.x+bias);
        }
    }
}

// temporal scores -> aT bf16 [n][ds][q][t] (zeros in masked region)
__global__ __launch_bounds__(256) void k_score_t(
    const short* __restrict__ qkt, const float* __restrict__ alphat_f,
    const float* __restrict__ alphat_b, short* __restrict__ aT)
{
    const int n = blockIdx.x >> 2, ds = blockIdx.x & 3, dir = ds>>1, s = ds&1;
    const int qoff = dir*32 + s*16, koff = 64 + dir*32 + s*16;
    const float alpha = dir ? alphat_b[s] : alphat_f[s];
    const int tid = threadIdx.x, w = tid>>6, lane = tid&63, lr = lane&15, lq = lane>>4;
    const short* qb = qkt + (size_t)n*409600;
    short* ao = aT + (size_t)(n*4+ds)*16384;
    const bf8 zf = {0,0,0,0,0,0,0,0};
    for (int ni = 0; ni < 2; ++ni) {
        const int nt = w*2+ni;
        for (int mt = 0; mt < 8; ++mt) {
            const int q = nt*16+lr, t0r = mt*16+lq*4;
            const bool skip = (dir==0) ? (mt < nt) : (mt > nt);
            if (skip) { s4 z = {0,0,0,0}; *(s4*)&ao[q*128 + t0r] = z; continue; }
            f4 acc = {0.f,0.f,0.f,0.f};
            for (int ks = 0; ks < 13; ++ks) {
                bf8 af, bf;
                if (ks==12 && lq>=2) { af = zf; bf = zf; }
                else {
                    af = *(const bf8*)&qb[(size_t)(mt*16+lr)*3200 + qoff*25 + ks*32 + lq*8];
                    bf = *(const bf8*)&qb[(size_t)(nt*16+lr)*3200 + koff*25 + ks*32 + lq*8];
                }
                acc = MFMA(af, bf, acc);
            }
            float r[4];
            #pragma unroll
            for (int j = 0; j < 4; ++j) {
                const int tt = t0r + j;
                const bool ok = (dir==0) ? (tt >= q) : (tt <= q);
                const float a = (j==0)?acc.x:((j==1)?acc.y:((j==2)?acc.z:acc.w));
                r[j] = ok ? tanhf(a*(1.f/400.f))*alpha : 0.f;
            }
            *(s4*)&ao[q*128 + t0r] = packf4(r[0],r[1],r[2],r[3]);
        }
    }
}

// ---------------------------------------------------------------------------
// Fused temporal aggregation (replaces 4x(k_pproj+k_uacc), one launch).
// block = (n, v), 4 waves; wave w owns o-tile w. For each ds:
//   PTl[o][t] = sum_c Y[t,v,c] * w_out_t[o][ds*64+c]        (MFMA -> LDS)
//   acc[o][q] += sum_t PTl[o][t] * aT[ds][q][t]             (MFMA, regs)
// acc kept in registers across all 4 ds; U written once (no RMW, no PT
// global round-trip). LDS 79.9 KB -> 2 blocks/CU.
// ---------------------------------------------------------------------------
__global__ __launch_bounds__(256) void k_tagg(
    const short* __restrict__ Y, const short* __restrict__ wb,
    const short* __restrict__ aT, short* __restrict__ U)
{
    const int n = blockIdx.x / 25, v = blockIdx.x % 25;
    const int tid = threadIdx.x, w = tid>>6, lane = tid&63, lr = lane&15, lq = lane>>4;
    __shared__ short ys[128][72];     // Y[t][c] for this v      18.4 KB
    __shared__ short wolds[64][72];   // w_out_t slice [o][64c]   9.2 KB
    __shared__ short pt[64][136];     // PTl [o][t]              17.4 KB
    __shared__ short ats[128][136];   // aT[ds] [q][t]           34.8 KB

    for (int i = tid; i < 128*8; i += 256) {
        const int t = i>>3, seg = i&7;
        *(bf8*)&ys[t][seg*8] = *(const bf8*)&Y[((size_t)n*3200 + t*25 + v)*64 + seg*8];
    }

    f4 acc[8];
    #pragma unroll
    for (int nt = 0; nt < 8; ++nt) { acc[nt].x=0.f; acc[nt].y=0.f; acc[nt].z=0.f; acc[nt].w=0.f; }

    for (int ds = 0; ds < 4; ++ds) {
        const int dir = ds>>1;
        __syncthreads();   // prev-ds pt/ats reads complete (and ys staged, iter 0)
        for (int i = tid; i < 64*8; i += 256) {
            const int o = i>>3, seg = i&7;
            *(bf8*)&wolds[o][seg*8] = *(const bf8*)&wb[30720 + o*256 + ds*64 + seg*8];
        }
        for (int i = tid; i < 128*16; i += 256) {
            const int q = i>>4, seg = i&15;
            *(bf8*)&ats[q][seg*8] = *(const bf8*)&aT[(size_t)(n*4+ds)*16384 + q*128 + seg*8];
        }
        __syncthreads();
        // PTl: A = ys (t rows), B = wolds (o rows) -> D[t][o];
        // lane writes 4 consecutive t at o = w*16+lr.
        {
            const bf8 b0 = *(const bf8*)&wolds[w*16+lr][lq*8];
            const bf8 b1 = *(const bf8*)&wolds[w*16+lr][32+lq*8];
            #pragma unroll
            for (int tt = 0; tt < 8; ++tt) {
                f4 p = {0.f,0.f,0.f,0.f};
                const bf8 a0 = *(const bf8*)&ys[tt*16+lr][lq*8];
                const bf8 a1 = *(const bf8*)&ys[tt*16+lr][32+lq*8];
                p = MFMA(a0,b0,p); p = MFMA(a1,b1,p);
                *(s4*)&pt[w*16+lr][tt*16+lq*4] = packf4(p.x,p.y,p.z,p.w);
            }
        }
        __syncthreads();
        // U accumulate: A = pt (o rows), B = ats (q rows) -> D[o][q]
        bf8 af[4];
        #pragma unroll
        for (int ks = 0; ks < 4; ++ks)
            af[ks] = *(const bf8*)&pt[w*16+lr][ks*32+lq*8];
        #pragma unroll
        for (int nt = 0; nt < 8; ++nt) {
            #pragma unroll
            for (int ks = 0; ks < 4; ++ks) {
                const bool skip = (dir==0) ? (ks*32+31 < nt*16) : (ks*32 > nt*16+15);
                if (skip) continue;
                const bf8 bf = *(const bf8*)&ats[nt*16+lr][ks*32+lq*8];
                acc[nt] = MFMA(af[ks], bf, acc[nt]);
            }
        }
    }
    // write U[q][v][o] once
    #pragma unroll
    for (int nt = 0; nt < 8; ++nt) {
        const int q = nt*16+lr, o0 = w*16+lq*4;
        *(s4*)&U[((size_t)(n*128+q)*25 + v)*64 + o0] =
            packf4(acc[nt].x, acc[nt].y, acc[nt].z, acc[nt].w);
    }
}

// temporal ff block: z1 = lrelu(y + u*sc1+sh1); Y = lrelu(y + BN(Wff@z1)) in-place
__global__ __launch_bounds__(256) void k_temporal(
    const short* __restrict__ U, short* __restrict__ Y, const short* __restrict__ wb,
    const float* __restrict__ b_out, const float* __restrict__ bn_out,
    const float* __restrict__ b_ff,  const float* __restrict__ bn_ff)
{
    const int n = blockIdx.x >> 5, qc = blockIdx.x & 31, q0 = qc*4;
    const int tid = threadIdx.x, w = tid>>6, lane = tid&63, lr = lane&15, lq = lane>>4;
    __shared__ short zs[112][72];
    __shared__ short z1[112][72];
    __shared__ short zout[112][72];
    __shared__ short wf[64][72];
    __shared__ float sc1s[64], sh1s[64], sc2s[64], sh2s[64];
    if (tid < 64) {
        float g=bn_out[tid], bb=bn_out[64+tid], m=bn_out[128+tid], vv=bn_out[192+tid];
        float inv = g*rsqrtf(vv+BN_EPS);
        sc1s[tid]=inv; sh1s[tid]=(b_out[tid]-m)*inv+bb;
        g=bn_ff[tid]; bb=bn_ff[64+tid]; m=bn_ff[128+tid]; vv=bn_ff[192+tid];
        inv = g*rsqrtf(vv+BN_EPS);
        sc2s[tid]=inv; sh2s[tid]=(b_ff[tid]-m)*inv+bb;
    }
    for (int i = tid; i < 64*8; i += 256) {
        const int o = i>>3, seg = i&7;
        *(bf8*)&wf[o][seg*8] = *(const bf8*)&wb[47104 + o*64 + seg*8];
    }
    __syncthreads();
    for (int i = tid; i < 112*8; i += 256) {
        const int row = i>>3, seg = i&7;
        bf8 yv = {0,0,0,0,0,0,0,0}, zv = yv;
        if (row < 100) {
            const int q = q0 + row/25, v = row%25;
            yv = *(const bf8*)&Y[((size_t)n*3200 + q*25 + v)*64 + seg*8];
            const bf8 uv = *(const bf8*)&U[((size_t)(n*128+q)*25 + v)*64 + seg*8];
            #pragma unroll
            for (int j = 0; j < 8; ++j) {
                const int o = seg*8+j;
                zv[j] = f2bs(lrelu(b2f(yv[j]) + b2f(uv[j])*sc1s[o] + sh1s[o]));
            }
        }
        *(bf8*)&zs[row][seg*8] = yv;
        *(bf8*)&z1[row][seg*8] = zv;
    }
    __syncthreads();
    const bf8 a0 = *(const bf8*)&wf[w*16+lr][lq*8];
    const bf8 a1 = *(const bf8*)&wf[w*16+lr][32+lq*8];
    for (int nt = 0; nt < 7; ++nt) {
        f4 acc = {0.f,0.f,0.f,0.f};
        const bf8 b0 = *(const bf8*)&z1[nt*16+lr][lq*8];
        const bf8 b1 = *(const bf8*)&z1[nt*16+lr][32+lq*8];
        acc = MFMA(a0,b0,acc); acc = MFMA(a1,b1,acc);
        const int px = nt*16+lr, o0 = w*16+lq*4;
        const s4 yr = *(const s4*)&zs[px][o0];
        const float r0 = lrelu(acc.x*sc2s[o0  ]+sh2s[o0  ]+b2f(yr.x));
        const float r1 = lrelu(acc.y*sc2s[o0+1]+sh2s[o0+1]+b2f(yr.y));
        const float r2 = lrelu(acc.z*sc2s[o0+2]+sh2s[o0+2]+b2f(yr.z));
        const float r3 = lrelu(acc.w*sc2s[o0+3]+sh2s[o0+3]+b2f(yr.w));
        *(s4*)&zout[px][o0] = packf4(r0,r1,r2,r3);
    }
    __syncthreads();
    for (int i = tid; i < 100*8; i += 256) {
        const int row = i>>3, seg = i&7;
        *(bf8*)&Y[((size_t)n*3200 + q0*25 + row)*64 + seg*8] = *(const bf8*)&zout[row][seg*8];
    }
}

// tcn: out[o][t][v] = lrelu(BN(sum_{dt,c} w[o][c][dt]*z[t+dt-3,v,c] + b) + z) f32
__global__ __launch_bounds__(256) void k_tcn(
    const short* __restrict__ Y, const short* __restrict__ wb,
    const float* __restrict__ b, const float* __restrict__ bn,
    float* __restrict__ out)
{
    const int n = blockIdx.x >> 5, tc = (blockIdx.x >> 1) & 15, oh = blockIdx.x & 1;
    const int t0 = tc*8;
    const int tid = threadIdx.x, w = tid>>6, lane = tid&63, lr = lane&15, lq = lane>>4;
    __shared__ short zs[352][72];
    __shared__ short wt[32][456];
    __shared__ short yout[208][40];
    __shared__ float scs[32], shs[32];
    if (tid < 32) {
        const int o = oh*32 + tid;
        const float g=bn[o], bb=bn[64+o], m=bn[128+o], vv=bn[192+o];
        const float inv = g*rsqrtf(vv+BN_EPS);
        scs[tid]=inv; shs[tid]=(b[o]-m)*inv+bb;
    }
    for (int i = tid; i < 352*8; i += 256) {
        const int row = i>>3, seg = i&7;
        bf8 val = {0,0,0,0,0,0,0,0};
        if (row < 350) {
            const int tlp = row/25, v = row%25, t = t0 - 3 + tlp;
            if (t >= 0 && t < 128)
                val = *(const bf8*)&Y[((size_t)n*3200 + t*25 + v)*64 + seg*8];
        }
        *(bf8*)&zs[row][seg*8] = val;
    }
    for (int i = tid; i < 32*57; i += 256) {
        const int o = i/57, seg = i%57;
        bf8 val = {0,0,0,0,0,0,0,0};
        if (seg < 56) val = *(const bf8*)&wb[51200 + (oh*32+o)*448 + seg*8];
        *(bf8*)&wt[o][seg*8] = val;
    }
    __syncthreads();
    for (int nn = 0; nn < 4; ++nn) {
        const int nt = w + nn*4;
        if (nt >= 13) break;
        for (int mt = 0; mt < 2; ++mt) {
            f4 acc = {0.f,0.f,0.f,0.f};
            for (int st = 0; st < 14; ++st) {
                const int dt = st>>1;
                const bf8 af = *(const bf8*)&wt[mt*16+lr][st*32+lq*8];
                const bf8 bf = *(const bf8*)&zs[nt*16 + lr + dt*25][(st&1)*32 + lq*8];
                acc = MFMA(af, bf, acc);
            }
            const int px = nt*16+lr, o0l = mt*16+lq*4;
            const s4 zr = *(const s4*)&zs[px+75][oh*32+o0l];
            const float r0 = lrelu(acc.x*scs[o0l  ]+shs[o0l  ]+b2f(zr.x));
            const float r1 = lrelu(acc.y*scs[o0l+1]+shs[o0l+1]+b2f(zr.y));
            const float r2 = lrelu(acc.z*scs[o0l+2]+shs[o0l+2]+b2f(zr.z));
            const float r3 = lrelu(acc.w*scs[o0l+3]+shs[o0l+3]+b2f(zr.w));
            *(s4*)&yout[px][o0l] = packf4(r0,r1,r2,r3);
        }
    }
    __syncthreads();
    for (int i = tid; i < 32*200; i += 256) {
        const int ol = i/200, p = i%200, tl = p/25, v = p%25;
        out[(size_t)n*204800 + (size_t)(oh*32+ol)*3200 + (t0+tl)*25 + v] = b2f(yout[p][ol]);
    }
}

// ---------------------------------------------------------------------------
extern "C" void kernel_launch(void* const* d_in, const int* in_sizes, int n_in,
                              void* d_out, int out_size, void* d_ws, size_t ws_size,
                              hipStream_t stream) {
    const float* x        = (const float*)d_in[0];
    const float* w_in_s   = (const float*)d_in[1];
    const float* b_in_s   = (const float*)d_in[2];
    const float* alphas   = (const float*)d_in[3];
    const float* att0s    = (const float*)d_in[4];
    const float* w_out_s  = (const float*)d_in[5];
    const float* b_out_s  = (const float*)d_in[6];
    const float* bn_out_s = (const float*)d_in[7];
    const float* w_ff_s   = (const float*)d_in[8];
    const float* b_ff_s   = (const float*)d_in[9];
    const float* bn_ff_s  = (const float*)d_in[10];
    const float* w_in_t   = (const float*)d_in[11];
    const float* b_in_t   = (const float*)d_in[12];
    const float* alphat_f = (const float*)d_in[13];
    const float* alphat_b = (const float*)d_in[14];
    const float* w_out_t  = (const float*)d_in[15];
    const float* b_out_t  = (const float*)d_in[16];
    const float* bn_out_t = (const float*)d_in[17];
    const float* b_ff_t   = (const float*)d_in[19];
    const float* bn_ff_t  = (const float*)d_in[20];
    const float* w_ff_t   = (const float*)d_in[18];
    const float* w_tcn    = (const float*)d_in[21];
    const float* b_tcn    = (const float*)d_in[22];
    const float* bn_tcn   = (const float*)d_in[23];
    float* out = (float*)d_out;
    char* ws = (char*)d_ws;

    short* wb    = (short*)(ws + 0);
    short* attnB = (short*)(ws + 4102144);
    short* Y     = (short*)(ws + 4888576);
    short* aT    = (short*)(ws + 57317376);
    short* XB    = (short*)(ws + 74094592);           // phase 1
    short* QKT   = (short*)(ws + 74094592);           // phase 2 (XB dead)
    short* U     = (short*)(ws + 74094592 + 52428800);

    k_prep<<<64, 256, 0, stream>>>(w_in_s, w_out_s, w_ff_s, w_in_t, w_out_t, w_ff_t, w_tcn, wb);
    k_x2b<<<2048, 256, 0, stream>>>(x, XB);
    k_attn_s<<<NN * 3, 256, 0, stream>>>(XB, wb, b_in_s, alphas, att0s, attnB);
    k_spatial<<<4096, 256, 0, stream>>>(XB, attnB, wb, b_out_s, bn_out_s, b_ff_s, bn_ff_s, Y);
    k_qkt<<<4096, 256, 0, stream>>>(Y, wb, b_in_t, QKT);
    k_score_t<<<512, 256, 0, stream>>>(QKT, alphat_f, alphat_b, aT);
    k_tagg<<<NN * 25, 256, 0, stream>>>(Y, wb, aT, U);
    k_temporal<<<4096, 256, 0, stream>>>(U, Y, wb, b_out_t, bn_out_t, b_ff_t, bn_ff_t);
    k_tcn<<<4096, 256, 0, stream>>>(Y, wb, b_tcn, bn_tcn, out);
}

// Round 2
// 780.627 us; speedup vs baseline: 1.0668x; 1.0668x over previous
//
#include <hip/hip_runtime.h>
#include <math.h>

#define NN   128
#define TTc  128
#define VVc  25
#define TV   3200
#define BN_EPS 1e-5f

typedef __attribute__((ext_vector_type(8))) short bf8;   // 8 bf16 in 4 VGPRs
typedef __attribute__((ext_vector_type(4))) short s4;    // 4 bf16 (b64)
typedef __attribute__((ext_vector_type(4))) float f4;    // MFMA accumulator

#define MFMA(a,b,c) __builtin_amdgcn_mfma_f32_16x16x32_bf16(a,b,c,0,0,0)

__device__ __forceinline__ float lrelu(float a){ return a>=0.f ? a : 0.1f*a; }
__device__ __forceinline__ short f2bs(float f){
    union{float f; unsigned u;} x; x.f = f;
    unsigned r = x.u + 0x7FFF + ((x.u>>16)&1);
    return (short)(r>>16);
}
__device__ __forceinline__ float b2f(short s){
    union{unsigned u; float f;} x; x.u = ((unsigned)(unsigned short)s)<<16; return x.f;
}
__device__ __forceinline__ s4 packf4(float a,float b,float c,float d){
    s4 r; r.x=f2bs(a); r.y=f2bs(b); r.z=f2bs(c); r.w=f2bs(d); return r;
}

// ---------------------------------------------------------------------------
// Workspace layout (total 178,952,192 B, proven OK):
//  wb bf16 weights       : byte 0
//  attnB bf16 [n][32v][96]: byte 4102144
//  Y  bf16 [n][3200][64] : byte 4888576
//  aT bf16 [n][4][q][t]  : byte 57317376
//  R  : byte 74094592 : XB -> QKT
//  U  : byte 74094592+52428800
// wb element offsets: w_in_s 0 [96][64]; w_out_s 6144 [64][192]; w_ff_s 18432
//  [64][64]; w_in_t 22528 [128][64]; w_out_t 30720 [64][256]; w_ff_t 47104
//  [64][64]; wt 51200 [64][448] (o, dt*64+c)
// ---------------------------------------------------------------------------

__global__ __launch_bounds__(256) void k_prep(
    const float* __restrict__ w_in_s, const float* __restrict__ w_out_s,
    const float* __restrict__ w_ff_s, const float* __restrict__ w_in_t,
    const float* __restrict__ w_out_t, const float* __restrict__ w_ff_t,
    const float* __restrict__ w_tcn, short* __restrict__ wb)
{
    const int total = 51200 + 64*448;
    for (int i = blockIdx.x*256 + threadIdx.x; i < total; i += gridDim.x*256) {
        float v;
        if      (i < 6144)  v = w_in_s[i];
        else if (i < 18432) v = w_out_s[i-6144];
        else if (i < 22528) v = w_ff_s[i-18432];
        else if (i < 30720) v = w_in_t[i-22528];
        else if (i < 47104) v = w_out_t[i-30720];
        else if (i < 51200) v = w_ff_t[i-47104];
        else { int j=i-51200; int o=j/448; int r=j%448; int dt=r>>6; int c=r&63;
               v = w_tcn[(o*64+c)*7 + dt]; }
        wb[i] = f2bs(v);
    }
}

// x f32 [n][c][t][v] -> XB bf16 pixel-major [n][t*25+v][64]
__global__ __launch_bounds__(256) void k_x2b(const float* __restrict__ x, short* __restrict__ XB)
{
    const int n = blockIdx.x >> 4, tc = blockIdx.x & 15, t0 = tc*8;
    const int tid = threadIdx.x;
    __shared__ float xs[64][201];
    const float* xb = x + (size_t)n*204800 + t0*25;
    for (int i = tid; i < 64*200; i += 256) { int c=i/200, p=i%200; xs[c][p] = xb[(size_t)c*3200 + p]; }
    __syncthreads();
    short* ob = XB + (size_t)n*204800 + t0*25*64;
    for (int i = tid; i < 200*64; i += 256) { int p=i>>6, c=i&63; ob[i] = f2bs(xs[c][p]); }
}

// ---------------------------------------------------------------------------
// Fused spatial attention scores (MFMA). grid = N*SS, 4 waves.
// ---------------------------------------------------------------------------
__global__ __launch_bounds__(256) void k_attn_s(
    const short* __restrict__ XB, const short* __restrict__ wb,
    const float* __restrict__ b_in_s, const float* __restrict__ alphas,
    const float* __restrict__ att0s, short* __restrict__ attnB)
{
    const int n = blockIdx.x / 3, s = blockIdx.x % 3;
    const int tid = threadIdx.x, w = tid>>6, lane = tid&63, lr = lane&15, lq = lane>>4;
    __shared__ short ys[208][72];     // staged pixels [px][64c]
    __shared__ short qkl[208][40];    // projected [px][32ch]: 0-15 q, 16-31 k
    __shared__ short wsl[32][72];     // weight rows (q 16 + k 16) x 64c
    __shared__ float bl[32];

    for (int i = tid; i < 32*8; i += 256) {
        const int cl = i>>3, seg = i&7;
        const int row = (cl < 16) ? (s*16 + cl) : (48 + s*16 + (cl-16));
        *(bf8*)&wsl[cl][seg*8] = *(const bf8*)&wb[row*64 + seg*8];
    }
    if (tid < 32) {
        const int row = (tid < 16) ? (s*16 + tid) : (48 + s*16 + (tid-16));
        bl[tid] = b_in_s[row];
    }

    const int mt = w>>1, sn = w&1;     // this wave's score tile (u-tile, v-tile)
    f4 acc = {0.f,0.f,0.f,0.f};

    for (int ch = 0; ch < 16; ++ch) {
        __syncthreads();   // qkl/ys from prev iter fully consumed
        for (int i = tid; i < 208*8; i += 256) {
            const int row = i>>3, seg = i&7;
            bf8 val = {0,0,0,0,0,0,0,0};
            if (row < 200)
                val = *(const bf8*)&XB[((size_t)n*3200 + ch*200 + row)*64 + seg*8];
            *(bf8*)&ys[row][seg*8] = val;
        }
        __syncthreads();
        // projection: wave w covers px-tiles {w, w+4, w+8, w+12}
        for (int nn = 0; nn < 4; ++nn) {
            const int nt2 = w + nn*4;
            if (nt2 >= 13) break;
            const bf8 b0 = *(const bf8*)&ys[nt2*16+lr][lq*8];
            const bf8 b1 = *(const bf8*)&ys[nt2*16+lr][32+lq*8];
            for (int mt2 = 0; mt2 < 2; ++mt2) {
                f4 pa = {0.f,0.f,0.f,0.f};
                const bf8 a0 = *(const bf8*)&wsl[mt2*16+lr][lq*8];
                const bf8 a1 = *(const bf8*)&wsl[mt2*16+lr][32+lq*8];
                pa = MFMA(a0,b0,pa); pa = MFMA(a1,b1,pa);
                const int px = nt2*16+lr, c0 = mt2*16+lq*4;
                *(s4*)&qkl[px][c0] =
                    packf4(pa.x+bl[c0], pa.y+bl[c0+1], pa.z+bl[c0+2], pa.w+bl[c0+3]);
            }
        }
        __syncthreads();
        // score accumulate: k = (t_local, c), 4 steps of 32
        for (int ks = 0; ks < 4; ++ks) {
            const int tl = ks*2 + (lq>>1);
            const bf8 af = *(const bf8*)&qkl[tl*25 + mt*16+lr][(lq&1)*8];
            const bf8 bf = *(const bf8*)&qkl[tl*25 + sn*16+lr][16 + (lq&1)*8];
            acc = MFMA(af, bf, acc);
        }
    }
    const float alpha = alphas[s];
    const int v = sn*16 + lr, u0 = mt*16 + lq*4;
    float r[4];
    #pragma unroll
    for (int j = 0; j < 4; ++j) {
        const int u = u0 + j;
        const float a = (j==0)?acc.x:((j==1)?acc.y:((j==2)?acc.z:acc.w));
        r[j] = (u < 25 && v < 25)
             ? tanhf(a*(1.f/2048.f))*alpha + att0s[s*625 + u*25 + v] : 0.f;
    }
    *(s4*)&attnB[(size_t)n*3072 + v*96 + s*32 + u0] = packf4(r[0],r[1],r[2],r[3]);
}

// ---------------------------------------------------------------------------
// fused spatial block (MFMA). block=(n, t-chunk4), wave w owns t=t0+w.
// ---------------------------------------------------------------------------
__global__ __launch_bounds__(256) void k_spatial(
    const short* __restrict__ XB, const short* __restrict__ attnB, const short* __restrict__ wb,
    const float* __restrict__ b_out, const float* __restrict__ bn_out,
    const float* __restrict__ b_ff,  const float* __restrict__ bn_ff,
    short* __restrict__ Y)
{
    const int n = blockIdx.x >> 5, tc = blockIdx.x & 31, t0 = tc*4;
    const int tid = threadIdx.x;
    const int w = tid>>6, lane = tid&63, lr = lane&15, lq = lane>>4;
    __shared__ short xs[4][32][72];
    __shared__ short wlo[64][200];
    __shared__ short wlf[64][72];
    __shared__ short ab[32][104];
    __shared__ short gsT[4][64][104];
    __shared__ short y1[4][32][72];
    __shared__ float sc1s[64], sh1s[64], sc2s[64], sh2s[64];

    for (int i = tid; i < 4*32*8; i += 256) {
        const int row = i>>3, seg = i&7, tl = row>>5, uv = row&31;
        bf8 val = {0,0,0,0,0,0,0,0};
        if (uv < 25) val = *(const bf8*)&XB[((size_t)n*3200 + (t0+tl)*25 + uv)*64 + seg*8];
        *(bf8*)&xs[tl][uv][seg*8] = val;
    }
    for (int i = tid; i < 64*24; i += 256) {
        const int o = i/24, seg = i%24;
        *(bf8*)&wlo[o][seg*8] = *(const bf8*)&wb[6144 + o*192 + seg*8];
    }
    for (int i = tid; i < 64*8; i += 256) {
        const int o = i>>3, seg = i&7;
        *(bf8*)&wlf[o][seg*8] = *(const bf8*)&wb[18432 + o*64 + seg*8];
    }
    for (int i = tid; i < 32*12; i += 256) {
        const int v = i/12, seg = i%12;
        *(bf8*)&ab[v][seg*8] = *(const bf8*)&attnB[(size_t)n*3072 + v*96 + seg*8];
    }
    if (tid < 64) {
        float g=bn_out[tid], bb=bn_out[64+tid], m=bn_out[128+tid], vv=bn_out[192+tid];
        float inv = g*rsqrtf(vv+BN_EPS);
        sc1s[tid]=inv; sh1s[tid]=(b_out[tid]-m)*inv+bb;
        g=bn_ff[tid]; bb=bn_ff[64+tid]; m=bn_ff[128+tid]; vv=bn_ff[192+tid];
        inv = g*rsqrtf(vv+BN_EPS);
        sc2s[tid]=inv; sh2s[tid]=(b_ff[tid]-m)*inv+bb;
    }
    __syncthreads();

    const int t = t0 + w;
    for (int s = 0; s < 3; ++s) {
        for (int mt = 0; mt < 2; ++mt) {
            const bf8 a0 = *(const bf8*)&xs[w][mt*16+lr][lq*8];
            const bf8 a1 = *(const bf8*)&xs[w][mt*16+lr][32+lq*8];
            for (int nt = 0; nt < 4; ++nt) {
                f4 acc = {0.f,0.f,0.f,0.f};
                const bf8 b0 = *(const bf8*)&wlo[nt*16+lr][s*64 + lq*8];
                const bf8 b1 = *(const bf8*)&wlo[nt*16+lr][s*64 + 32 + lq*8];
                acc = MFMA(a0,b0,acc); acc = MFMA(a1,b1,acc);
                const int o = nt*16+lr, u0 = mt*16+lq*4;
                *(s4*)&gsT[w][o][s*32+u0] = packf4(acc.x,acc.y,acc.z,acc.w);
            }
        }
    }
    for (int mt = 0; mt < 4; ++mt) {
        const bf8 a0 = *(const bf8*)&gsT[w][mt*16+lr][lq*8];
        const bf8 a1 = *(const bf8*)&gsT[w][mt*16+lr][32+lq*8];
        const bf8 a2 = *(const bf8*)&gsT[w][mt*16+lr][64+lq*8];
        for (int nt = 0; nt < 2; ++nt) {
            f4 acc = {0.f,0.f,0.f,0.f};
            const bf8 b0 = *(const bf8*)&ab[nt*16+lr][lq*8];
            const bf8 b1 = *(const bf8*)&ab[nt*16+lr][32+lq*8];
            const bf8 b2 = *(const bf8*)&ab[nt*16+lr][64+lq*8];
            acc = MFMA(a0,b0,acc); acc = MFMA(a1,b1,acc); acc = MFMA(a2,b2,acc);
            const int v = nt*16+lr, o0 = mt*16+lq*4;
            const s4 xr = *(const s4*)&xs[w][v][o0];
            const float r0 = lrelu(acc.x*sc1s[o0  ]+sh1s[o0  ]+b2f(xr.x));
            const float r1 = lrelu(acc.y*sc1s[o0+1]+sh1s[o0+1]+b2f(xr.y));
            const float r2 = lrelu(acc.z*sc1s[o0+2]+sh1s[o0+2]+b2f(xr.z));
            const float r3 = lrelu(acc.w*sc1s[o0+3]+sh1s[o0+3]+b2f(xr.w));
            *(s4*)&y1[w][v][o0] = packf4(r0,r1,r2,r3);
        }
    }
    for (int mt = 0; mt < 4; ++mt) {
        const bf8 a0 = *(const bf8*)&wlf[mt*16+lr][lq*8];
        const bf8 a1 = *(const bf8*)&wlf[mt*16+lr][32+lq*8];
        for (int nt = 0; nt < 2; ++nt) {
            f4 acc = {0.f,0.f,0.f,0.f};
            const bf8 b0 = *(const bf8*)&y1[w][nt*16+lr][lq*8];
            const bf8 b1 = *(const bf8*)&y1[w][nt*16+lr][32+lq*8];
            acc = MFMA(a0,b0,acc); acc = MFMA(a1,b1,acc);
            const int v = nt*16+lr, o0 = mt*16+lq*4;
            if (v < 25) {
                const s4 xr = *(const s4*)&xs[w][v][o0];
                const float r0 = lrelu(acc.x*sc2s[o0  ]+sh2s[o0  ]+b2f(xr.x));
                const float r1 = lrelu(acc.y*sc2s[o0+1]+sh2s[o0+1]+b2f(xr.y));
                const float r2 = lrelu(acc.z*sc2s[o0+2]+sh2s[o0+2]+b2f(xr.z));
                const float r3 = lrelu(acc.w*sc2s[o0+3]+sh2s[o0+3]+b2f(xr.w));
                *(s4*)&Y[((size_t)n*3200 + t*25 + v)*64 + o0] = packf4(r0,r1,r2,r3);
            }
        }
    }
}

// temporal q/k proj -> QKT bf16 [n][t][128oc][25v]
__global__ __launch_bounds__(256) void k_qkt(
    const short* __restrict__ Y, const short* __restrict__ wb,
    const float* __restrict__ b_in_t, short* __restrict__ qkt)
{
    const int n = blockIdx.x >> 5, tc = blockIdx.x & 31, t0 = tc*4;
    const int tid = threadIdx.x;
    const int w = tid>>6, lane = tid&63, lr = lane&15, lq = lane>>4;
    __shared__ short ys[4][32][72];
    __shared__ short wi[128][72];
    for (int i = tid; i < 4*32*8; i += 256) {
        const int row = i>>3, seg = i&7, tl = row>>5, v = row&31;
        bf8 val = {0,0,0,0,0,0,0,0};
        if (v < 25) val = *(const bf8*)&Y[((size_t)n*3200 + (t0+tl)*25 + v)*64 + seg*8];
        *(bf8*)&ys[tl][v][seg*8] = val;
    }
    for (int i = tid; i < 128*8; i += 256) {
        const int o = i>>3, seg = i&7;
        *(bf8*)&wi[o][seg*8] = *(const bf8*)&wb[22528 + o*64 + seg*8];
    }
    __syncthreads();
    for (int mi = 0; mi < 2; ++mi) {
        const int mt = w*2+mi, tl = mt>>1, vh = mt&1;
        const bf8 a0 = *(const bf8*)&ys[tl][vh*16+lr][lq*8];
        const bf8 a1 = *(const bf8*)&ys[tl][vh*16+lr][32+lq*8];
        for (int nt = 0; nt < 8; ++nt) {
            f4 acc = {0.f,0.f,0.f,0.f};
            const bf8 b0 = *(const bf8*)&wi[nt*16+lr][lq*8];
            const bf8 b1 = *(const bf8*)&wi[nt*16+lr][32+lq*8];
            acc = MFMA(a0,b0,acc); acc = MFMA(a1,b1,acc);
            const int oc = nt*16+lr, v0 = vh*16+lq*4, t = t0+tl;
            const float bias = b_in_t[oc];
            const size_t base = (size_t)n*409600 + (size_t)t*3200 + oc*25 + v0;
            if (v0 < 24)
                *(s4*)&qkt[base] = packf4(acc.x+bias, acc.y+bias, acc.z+bias, acc.w+bias);
            else if (v0 == 24)
                qkt[base] = f2bs(acc.x+bias);
        }
    }
}

// temporal scores -> aT bf16 [n][ds][q][t] (zeros in masked region)
__global__ __launch_bounds__(256) void k_score_t(
    const short* __restrict__ qkt, const float* __restrict__ alphat_f,
    const float* __restrict__ alphat_b, short* __restrict__ aT)
{
    const int n = blockIdx.x >> 2, ds = blockIdx.x & 3, dir = ds>>1, s = ds&1;
    const int qoff = dir*32 + s*16, koff = 64 + dir*32 + s*16;
    const float alpha = dir ? alphat_b[s] : alphat_f[s];
    const int tid = threadIdx.x, w = tid>>6, lane = tid&63, lr = lane&15, lq = lane>>4;
    const short* qb = qkt + (size_t)n*409600;
    short* ao = aT + (size_t)(n*4+ds)*16384;
    const bf8 zf = {0,0,0,0,0,0,0,0};
    for (int ni = 0; ni < 2; ++ni) {
        const int nt = w*2+ni;
        for (int mt = 0; mt < 8; ++mt) {
            const int q = nt*16+lr, t0r = mt*16+lq*4;
            const bool skip = (dir==0) ? (mt < nt) : (mt > nt);
            if (skip) { s4 z = {0,0,0,0}; *(s4*)&ao[q*128 + t0r] = z; continue; }
            f4 acc = {0.f,0.f,0.f,0.f};
            for (int ks = 0; ks < 13; ++ks) {
                bf8 af, bf;
                if (ks==12 && lq>=2) { af = zf; bf = zf; }
                else {
                    af = *(const bf8*)&qb[(size_t)(mt*16+lr)*3200 + qoff*25 + ks*32 + lq*8];
                    bf = *(const bf8*)&qb[(size_t)(nt*16+lr)*3200 + koff*25 + ks*32 + lq*8];
                }
                acc = MFMA(af, bf, acc);
            }
            float r[4];
            #pragma unroll
            for (int j = 0; j < 4; ++j) {
                const int tt = t0r + j;
                const bool ok = (dir==0) ? (tt >= q) : (tt <= q);
                const float a = (j==0)?acc.x:((j==1)?acc.y:((j==2)?acc.z:acc.w));
                r[j] = ok ? tanhf(a*(1.f/400.f))*alpha : 0.f;
            }
            *(s4*)&ao[q*128 + t0r] = packf4(r[0],r[1],r[2],r[3]);
        }
    }
}

// ---------------------------------------------------------------------------
// Fused temporal aggregation. block = (n, v), 4 waves; wave w owns o-tile w.
// ---------------------------------------------------------------------------
__global__ __launch_bounds__(256) void k_tagg(
    const short* __restrict__ Y, const short* __restrict__ wb,
    const short* __restrict__ aT, short* __restrict__ U)
{
    const int n = blockIdx.x / 25, v = blockIdx.x % 25;
    const int tid = threadIdx.x, w = tid>>6, lane = tid&63, lr = lane&15, lq = lane>>4;
    __shared__ short ys[128][72];     // Y[t][c] for this v      18.4 KB
    __shared__ short wolds[64][72];   // w_out_t slice [o][64c]   9.2 KB
    __shared__ short pt[64][136];     // PTl [o][t]              17.4 KB
    __shared__ short ats[128][136];   // aT[ds] [q][t]           34.8 KB

    for (int i = tid; i < 128*8; i += 256) {
        const int t = i>>3, seg = i&7;
        *(bf8*)&ys[t][seg*8] = *(const bf8*)&Y[((size_t)n*3200 + t*25 + v)*64 + seg*8];
    }

    f4 acc[8];
    #pragma unroll
    for (int nt = 0; nt < 8; ++nt) { acc[nt].x=0.f; acc[nt].y=0.f; acc[nt].z=0.f; acc[nt].w=0.f; }

    for (int ds = 0; ds < 4; ++ds) {
        const int dir = ds>>1;
        __syncthreads();   // prev-ds pt/ats reads complete (and ys staged, iter 0)
        for (int i = tid; i < 64*8; i += 256) {
            const int o = i>>3, seg = i&7;
            *(bf8*)&wolds[o][seg*8] = *(const bf8*)&wb[30720 + o*256 + ds*64 + seg*8];
        }
        for (int i = tid; i < 128*16; i += 256) {
            const int q = i>>4, seg = i&15;
            *(bf8*)&ats[q][seg*8] = *(const bf8*)&aT[(size_t)(n*4+ds)*16384 + q*128 + seg*8];
        }
        __syncthreads();
        // PTl: A = ys (t rows), B = wolds (o rows) -> D[t][o];
        {
            const bf8 b0 = *(const bf8*)&wolds[w*16+lr][lq*8];
            const bf8 b1 = *(const bf8*)&wolds[w*16+lr][32+lq*8];
            #pragma unroll
            for (int tt = 0; tt < 8; ++tt) {
                f4 p = {0.f,0.f,0.f,0.f};
                const bf8 a0 = *(const bf8*)&ys[tt*16+lr][lq*8];
                const bf8 a1 = *(const bf8*)&ys[tt*16+lr][32+lq*8];
                p = MFMA(a0,b0,p); p = MFMA(a1,b1,p);
                *(s4*)&pt[w*16+lr][tt*16+lq*4] = packf4(p.x,p.y,p.z,p.w);
            }
        }
        __syncthreads();
        // U accumulate: A = pt (o rows), B = ats (q rows) -> D[o][q]
        bf8 af[4];
        #pragma unroll
        for (int ks = 0; ks < 4; ++ks)
            af[ks] = *(const bf8*)&pt[w*16+lr][ks*32+lq*8];
        #pragma unroll
        for (int nt = 0; nt < 8; ++nt) {
            #pragma unroll
            for (int ks = 0; ks < 4; ++ks) {
                const bool skip = (dir==0) ? (ks*32+31 < nt*16) : (ks*32 > nt*16+15);
                if (skip) continue;
                const bf8 bf = *(const bf8*)&ats[nt*16+lr][ks*32+lq*8];
                acc[nt] = MFMA(af[ks], bf, acc[nt]);
            }
        }
    }
    // write U[q][v][o] once
    #pragma unroll
    for (int nt = 0; nt < 8; ++nt) {
        const int q = nt*16+lr, o0 = w*16+lq*4;
        *(s4*)&U[((size_t)(n*128+q)*25 + v)*64 + o0] =
            packf4(acc[nt].x, acc[nt].y, acc[nt].z, acc[nt].w);
    }
}

// temporal ff block: z1 = lrelu(y + u*sc1+sh1); Y = lrelu(y + BN(Wff@z1)) in-place
__global__ __launch_bounds__(256) void k_temporal(
    const short* __restrict__ U, short* __restrict__ Y, const short* __restrict__ wb,
    const float* __restrict__ b_out, const float* __restrict__ bn_out,
    const float* __restrict__ b_ff,  const float* __restrict__ bn_ff)
{
    const int n = blockIdx.x >> 5, qc = blockIdx.x & 31, q0 = qc*4;
    const int tid = threadIdx.x, w = tid>>6, lane = tid&63, lr = lane&15, lq = lane>>4;
    __shared__ short zs[112][72];
    __shared__ short z1[112][72];
    __shared__ short zout[112][72];
    __shared__ short wf[64][72];
    __shared__ float sc1s[64], sh1s[64], sc2s[64], sh2s[64];
    if (tid < 64) {
        float g=bn_out[tid], bb=bn_out[64+tid], m=bn_out[128+tid], vv=bn_out[192+tid];
        float inv = g*rsqrtf(vv+BN_EPS);
        sc1s[tid]=inv; sh1s[tid]=(b_out[tid]-m)*inv+bb;
        g=bn_ff[tid]; bb=bn_ff[64+tid]; m=bn_ff[128+tid]; vv=bn_ff[192+tid];
        inv = g*rsqrtf(vv+BN_EPS);
        sc2s[tid]=inv; sh2s[tid]=(b_ff[tid]-m)*inv+bb;
    }
    for (int i = tid; i < 64*8; i += 256) {
        const int o = i>>3, seg = i&7;
        *(bf8*)&wf[o][seg*8] = *(const bf8*)&wb[47104 + o*64 + seg*8];
    }
    __syncthreads();
    for (int i = tid; i < 112*8; i += 256) {
        const int row = i>>3, seg = i&7;
        bf8 yv = {0,0,0,0,0,0,0,0}, zv = yv;
        if (row < 100) {
            const int q = q0 + row/25, v = row%25;
            yv = *(const bf8*)&Y[((size_t)n*3200 + q*25 + v)*64 + seg*8];
            const bf8 uv = *(const bf8*)&U[((size_t)(n*128+q)*25 + v)*64 + seg*8];
            #pragma unroll
            for (int j = 0; j < 8; ++j) {
                const int o = seg*8+j;
                zv[j] = f2bs(lrelu(b2f(yv[j]) + b2f(uv[j])*sc1s[o] + sh1s[o]));
            }
        }
        *(bf8*)&zs[row][seg*8] = yv;
        *(bf8*)&z1[row][seg*8] = zv;
    }
    __syncthreads();
    const bf8 a0 = *(const bf8*)&wf[w*16+lr][lq*8];
    const bf8 a1 = *(const bf8*)&wf[w*16+lr][32+lq*8];
    for (int nt = 0; nt < 7; ++nt) {
        f4 acc = {0.f,0.f,0.f,0.f};
        const bf8 b0 = *(const bf8*)&z1[nt*16+lr][lq*8];
        const bf8 b1 = *(const bf8*)&z1[nt*16+lr][32+lq*8];
        acc = MFMA(a0,b0,acc); acc = MFMA(a1,b1,acc);
        const int px = nt*16+lr, o0 = w*16+lq*4;
        const s4 yr = *(const s4*)&zs[px][o0];
        const float r0 = lrelu(acc.x*sc2s[o0  ]+sh2s[o0  ]+b2f(yr.x));
        const float r1 = lrelu(acc.y*sc2s[o0+1]+sh2s[o0+1]+b2f(yr.y));
        const float r2 = lrelu(acc.z*sc2s[o0+2]+sh2s[o0+2]+b2f(yr.z));
        const float r3 = lrelu(acc.w*sc2s[o0+3]+sh2s[o0+3]+b2f(yr.w));
        *(s4*)&zout[px][o0] = packf4(r0,r1,r2,r3);
    }
    __syncthreads();
    for (int i = tid; i < 100*8; i += 256) {
        const int row = i>>3, seg = i&7;
        *(bf8*)&Y[((size_t)n*3200 + q0*25 + row)*64 + seg*8] = *(const bf8*)&zout[row][seg*8];
    }
}

// ---------------------------------------------------------------------------
// tcn: out[o][t][v] = lrelu(BN(sum_{dt,c} w[o][c][dt]*z[t+dt-3,v,c] + b) + z)
// Rewritten: weights af[2][14] live in registers (global-loaded, L2-resident),
// pixel fragments bf[14] hoisted per nn and reused across both mt.
// LDS reads in hot loop: 448 -> 56 per wave. LDS 96.7 KB -> 67.6 KB
// (wt array removed) -> 2 blocks/CU via __launch_bounds__(256,2).
// ---------------------------------------------------------------------------
__global__ __launch_bounds__(256, 2) void k_tcn(
    const short* __restrict__ Y, const short* __restrict__ wb,
    const float* __restrict__ b, const float* __restrict__ bn,
    float* __restrict__ out)
{
    const int n = blockIdx.x >> 5, tc = (blockIdx.x >> 1) & 15, oh = blockIdx.x & 1;
    const int t0 = tc*8;
    const int tid = threadIdx.x, w = tid>>6, lane = tid&63, lr = lane&15, lq = lane>>4;
    __shared__ short zs[352][72];
    __shared__ short yout[208][40];
    __shared__ float scs[32], shs[32];

    // weights -> registers (rows o = oh*32 + mt*16 + lr; issued first so the
    // global loads overlap the LDS staging below)
    bf8 af[2][14];
    #pragma unroll
    for (int mt = 0; mt < 2; ++mt)
        #pragma unroll
        for (int st = 0; st < 14; ++st)
            af[mt][st] = *(const bf8*)&wb[51200 + (oh*32 + mt*16 + lr)*448 + st*32 + lq*8];

    if (tid < 32) {
        const int o = oh*32 + tid;
        const float g=bn[o], bb=bn[64+o], m=bn[128+o], vv=bn[192+o];
        const float inv = g*rsqrtf(vv+BN_EPS);
        scs[tid]=inv; shs[tid]=(b[o]-m)*inv+bb;
    }
    for (int i = tid; i < 352*8; i += 256) {
        const int row = i>>3, seg = i&7;
        bf8 val = {0,0,0,0,0,0,0,0};
        if (row < 350) {
            const int tlp = row/25, v = row%25, t = t0 - 3 + tlp;
            if (t >= 0 && t < 128)
                val = *(const bf8*)&Y[((size_t)n*3200 + t*25 + v)*64 + seg*8];
        }
        *(bf8*)&zs[row][seg*8] = val;
    }
    __syncthreads();
    for (int nn = 0; nn < 4; ++nn) {
        const int nt = w + nn*4;
        if (nt >= 13) break;
        // pixel fragments for this nt, shared by both mt
        bf8 bfr[14];
        #pragma unroll
        for (int st = 0; st < 14; ++st)
            bfr[st] = *(const bf8*)&zs[nt*16 + lr + (st>>1)*25][(st&1)*32 + lq*8];
        #pragma unroll
        for (int mt = 0; mt < 2; ++mt) {
            f4 ac0 = {0.f,0.f,0.f,0.f}, ac1 = {0.f,0.f,0.f,0.f};
            #pragma unroll
            for (int st = 0; st < 14; st += 2) {
                ac0 = MFMA(af[mt][st],   bfr[st],   ac0);
                ac1 = MFMA(af[mt][st+1], bfr[st+1], ac1);
            }
            const float ax = ac0.x+ac1.x, ay = ac0.y+ac1.y,
                        az = ac0.z+ac1.z, aw = ac0.w+ac1.w;
            const int px = nt*16+lr, o0l = mt*16+lq*4;
            const s4 zr = *(const s4*)&zs[px+75][oh*32+o0l];
            const float r0 = lrelu(ax*scs[o0l  ]+shs[o0l  ]+b2f(zr.x));
            const float r1 = lrelu(ay*scs[o0l+1]+shs[o0l+1]+b2f(zr.y));
            const float r2 = lrelu(az*scs[o0l+2]+shs[o0l+2]+b2f(zr.z));
            const float r3 = lrelu(aw*scs[o0l+3]+shs[o0l+3]+b2f(zr.w));
            *(s4*)&yout[px][o0l] = packf4(r0,r1,r2,r3);
        }
    }
    __syncthreads();
    for (int i = tid; i < 32*200; i += 256) {
        const int ol = i/200, p = i%200, tl = p/25, v = p%25;
        out[(size_t)n*204800 + (size_t)(oh*32+ol)*3200 + (t0+tl)*25 + v] = b2f(yout[p][ol]);
    }
}

// ---------------------------------------------------------------------------
extern "C" void kernel_launch(void* const* d_in, const int* in_sizes, int n_in,
                              void* d_out, int out_size, void* d_ws, size_t ws_size,
                              hipStream_t stream) {
    const float* x        = (const float*)d_in[0];
    const float* w_in_s   = (const float*)d_in[1];
    const float* b_in_s   = (const float*)d_in[2];
    const float* alphas   = (const float*)d_in[3];
    const float* att0s    = (const float*)d_in[4];
    const float* w_out_s  = (const float*)d_in[5];
    const float* b_out_s  = (const float*)d_in[6];
    const float* bn_out_s = (const float*)d_in[7];
    const float* w_ff_s   = (const float*)d_in[8];
    const float* b_ff_s   = (const float*)d_in[9];
    const float* bn_ff_s  = (const float*)d_in[10];
    const float* w_in_t   = (const float*)d_in[11];
    const float* b_in_t   = (const float*)d_in[12];
    const float* alphat_f = (const float*)d_in[13];
    const float* alphat_b = (const float*)d_in[14];
    const float* w_out_t  = (const float*)d_in[15];
    const float* b_out_t  = (const float*)d_in[16];
    const float* bn_out_t = (const float*)d_in[17];
    const float* w_ff_t   = (const float*)d_in[18];
    const float* b_ff_t   = (const float*)d_in[19];
    const float* bn_ff_t  = (const float*)d_in[20];
    const float* w_tcn    = (const float*)d_in[21];
    const float* b_tcn    = (const float*)d_in[22];
    const float* bn_tcn   = (const float*)d_in[23];
    float* out = (float*)d_out;
    char* ws = (char*)d_ws;

    short* wb    = (short*)(ws + 0);
    short* attnB = (short*)(ws + 4102144);
    short* Y     = (short*)(ws + 4888576);
    short* aT    = (short*)(ws + 57317376);
    short* XB    = (short*)(ws + 74094592);           // phase 1
    short* QKT   = (short*)(ws + 74094592);           // phase 2 (XB dead)
    short* U     = (short*)(ws + 74094592 + 52428800);

    k_prep<<<64, 256, 0, stream>>>(w_in_s, w_out_s, w_ff_s, w_in_t, w_out_t, w_ff_t, w_tcn, wb);
    k_x2b<<<2048, 256, 0, stream>>>(x, XB);
    k_attn_s<<<NN * 3, 256, 0, stream>>>(XB, wb, b_in_s, alphas, att0s, attnB);
    k_spatial<<<4096, 256, 0, stream>>>(XB, attnB, wb, b_out_s, bn_out_s, b_ff_s, bn_ff_s, Y);
    k_qkt<<<4096, 256, 0, stream>>>(Y, wb, b_in_t, QKT);
    k_score_t<<<512, 256, 0, stream>>>(QKT, alphat_f, alphat_b, aT);
    k_tagg<<<NN * 25, 256, 0, stream>>>(Y, wb, aT, U);
    k_temporal<<<4096, 256, 0, stream>>>(U, Y, wb, b_out_t, bn_out_t, b_ff_t, bn_ff_t);
    k_tcn<<<4096, 256, 0, stream>>>(Y, wb, b_tcn, bn_tcn, out);
}

// Round 3
// 769.975 us; speedup vs baseline: 1.0815x; 1.0138x over previous
//
#include <hip/hip_runtime.h>
#include <math.h>

#define NN   128
#define TTc  128
#define VVc  25
#define TV   3200
#define BN_EPS 1e-5f

typedef __attribute__((ext_vector_type(8))) short bf8;   // 8 bf16 in 4 VGPRs
typedef __attribute__((ext_vector_type(4))) short s4;    // 4 bf16 (b64)
typedef __attribute__((ext_vector_type(4))) float f4;    // MFMA accumulator

#define MFMA(a,b,c) __builtin_amdgcn_mfma_f32_16x16x32_bf16(a,b,c,0,0,0)

__device__ __forceinline__ float lrelu(float a){ return a>=0.f ? a : 0.1f*a; }
__device__ __forceinline__ short f2bs(float f){
    union{float f; unsigned u;} x; x.f = f;
    unsigned r = x.u + 0x7FFF + ((x.u>>16)&1);
    return (short)(r>>16);
}
__device__ __forceinline__ float b2f(short s){
    union{unsigned u; float f;} x; x.u = ((unsigned)(unsigned short)s)<<16; return x.f;
}
__device__ __forceinline__ s4 packf4(float a,float b,float c,float d){
    s4 r; r.x=f2bs(a); r.y=f2bs(b); r.z=f2bs(c); r.w=f2bs(d); return r;
}

// ---------------------------------------------------------------------------
// Workspace layout (total 178,952,192 B, proven OK):
//  wb bf16 weights       : byte 0
//  attnB bf16 [n][32v][96]: byte 4102144
//  Y  bf16 [n][3200][64] : byte 4888576
//  aT bf16 [n][4][q][t]  : byte 57317376
//  R  : byte 74094592 : XB -> QKT
//  U  : byte 74094592+52428800
// wb element offsets: w_in_s 0 [96][64]; w_out_s 6144 [64][192]; w_ff_s 18432
//  [64][64]; w_in_t 22528 [128][64]; w_out_t 30720 [64][256]; w_ff_t 47104
//  [64][64]; wt 51200 [64][448] (o, dt*64+c)
// ---------------------------------------------------------------------------

__global__ __launch_bounds__(256) void k_prep(
    const float* __restrict__ w_in_s, const float* __restrict__ w_out_s,
    const float* __restrict__ w_ff_s, const float* __restrict__ w_in_t,
    const float* __restrict__ w_out_t, const float* __restrict__ w_ff_t,
    const float* __restrict__ w_tcn, short* __restrict__ wb)
{
    const int total = 51200 + 64*448;
    for (int i = blockIdx.x*256 + threadIdx.x; i < total; i += gridDim.x*256) {
        float v;
        if      (i < 6144)  v = w_in_s[i];
        else if (i < 18432) v = w_out_s[i-6144];
        else if (i < 22528) v = w_ff_s[i-18432];
        else if (i < 30720) v = w_in_t[i-22528];
        else if (i < 47104) v = w_out_t[i-30720];
        else if (i < 51200) v = w_ff_t[i-47104];
        else { int j=i-51200; int o=j/448; int r=j%448; int dt=r>>6; int c=r&63;
               v = w_tcn[(o*64+c)*7 + dt]; }
        wb[i] = f2bs(v);
    }
}

// x f32 [n][c][t][v] -> XB bf16 pixel-major [n][t*25+v][64]
// [203] pad: lane stride 4 rows = 812 dw == 12 mod 32 -> 2-way (free).
__global__ __launch_bounds__(256) void k_x2b(const float* __restrict__ x, short* __restrict__ XB)
{
    const int n = blockIdx.x >> 4, tc = blockIdx.x & 15, t0 = tc*8;
    const int tid = threadIdx.x;
    __shared__ float xs[64][203];
    const float* xb = x + (size_t)n*204800 + t0*25;
    for (int i = tid; i < 64*200; i += 256) { int c=i/200, p=i%200; xs[c][p] = xb[(size_t)c*3200 + p]; }
    __syncthreads();
    short* ob = XB + (size_t)n*204800 + t0*25*64;
    for (int i = tid; i < 200*16; i += 256) {
        const int p = i>>4, c0 = (i&15)<<2;
        *(s4*)&ob[p*64 + c0] = packf4(xs[c0][p], xs[c0+1][p], xs[c0+2][p], xs[c0+3][p]);
    }
}

// ---------------------------------------------------------------------------
// Fused spatial attention scores (MFMA). grid = N*SS, 4 waves.
// ---------------------------------------------------------------------------
__global__ __launch_bounds__(256) void k_attn_s(
    const short* __restrict__ XB, const short* __restrict__ wb,
    const float* __restrict__ b_in_s, const float* __restrict__ alphas,
    const float* __restrict__ att0s, short* __restrict__ attnB)
{
    const int n = blockIdx.x / 3, s = blockIdx.x % 3;
    const int tid = threadIdx.x, w = tid>>6, lane = tid&63, lr = lane&15, lq = lane>>4;
    __shared__ short ys[208][72];     // staged pixels [px][64c]
    __shared__ short qkl[208][40];    // projected [px][32ch]: 0-15 q, 16-31 k
    __shared__ short wsl[32][72];     // weight rows (q 16 + k 16) x 64c
    __shared__ float bl[32];

    for (int i = tid; i < 32*8; i += 256) {
        const int cl = i>>3, seg = i&7;
        const int row = (cl < 16) ? (s*16 + cl) : (48 + s*16 + (cl-16));
        *(bf8*)&wsl[cl][seg*8] = *(const bf8*)&wb[row*64 + seg*8];
    }
    if (tid < 32) {
        const int row = (tid < 16) ? (s*16 + tid) : (48 + s*16 + (tid-16));
        bl[tid] = b_in_s[row];
    }

    const int mt = w>>1, sn = w&1;     // this wave's score tile (u-tile, v-tile)
    f4 acc = {0.f,0.f,0.f,0.f};

    for (int ch = 0; ch < 16; ++ch) {
        __syncthreads();   // qkl/ys from prev iter fully consumed
        for (int i = tid; i < 208*8; i += 256) {
            const int row = i>>3, seg = i&7;
            bf8 val = {0,0,0,0,0,0,0,0};
            if (row < 200)
                val = *(const bf8*)&XB[((size_t)n*3200 + ch*200 + row)*64 + seg*8];
            *(bf8*)&ys[row][seg*8] = val;
        }
        __syncthreads();
        // projection: wave w covers px-tiles {w, w+4, w+8, w+12}
        for (int nn = 0; nn < 4; ++nn) {
            const int nt2 = w + nn*4;
            if (nt2 >= 13) break;
            const bf8 b0 = *(const bf8*)&ys[nt2*16+lr][lq*8];
            const bf8 b1 = *(const bf8*)&ys[nt2*16+lr][32+lq*8];
            for (int mt2 = 0; mt2 < 2; ++mt2) {
                f4 pa = {0.f,0.f,0.f,0.f};
                const bf8 a0 = *(const bf8*)&wsl[mt2*16+lr][lq*8];
                const bf8 a1 = *(const bf8*)&wsl[mt2*16+lr][32+lq*8];
                pa = MFMA(a0,b0,pa); pa = MFMA(a1,b1,pa);
                const int px = nt2*16+lr, c0 = mt2*16+lq*4;
                *(s4*)&qkl[px][c0] =
                    packf4(pa.x+bl[c0], pa.y+bl[c0+1], pa.z+bl[c0+2], pa.w+bl[c0+3]);
            }
        }
        __syncthreads();
        // score accumulate: k = (t_local, c), 4 steps of 32
        for (int ks = 0; ks < 4; ++ks) {
            const int tl = ks*2 + (lq>>1);
            const bf8 af = *(const bf8*)&qkl[tl*25 + mt*16+lr][(lq&1)*8];
            const bf8 bf = *(const bf8*)&qkl[tl*25 + sn*16+lr][16 + (lq&1)*8];
            acc = MFMA(af, bf, acc);
        }
    }
    const float alpha = alphas[s];
    const int v = sn*16 + lr, u0 = mt*16 + lq*4;
    float r[4];
    #pragma unroll
    for (int j = 0; j < 4; ++j) {
        const int u = u0 + j;
        const float a = (j==0)?acc.x:((j==1)?acc.y:((j==2)?acc.z:acc.w));
        r[j] = (u < 25 && v < 25)
             ? tanhf(a*(1.f/2048.f))*alpha + att0s[s*625 + u*25 + v] : 0.f;
    }
    *(s4*)&attnB[(size_t)n*3072 + v*96 + s*32 + u0] = packf4(r[0],r[1],r[2],r[3]);
}

// ---------------------------------------------------------------------------
// fused spatial block (MFMA). block=(n, t-chunk4), wave w owns t=t0+w.
// ---------------------------------------------------------------------------
__global__ __launch_bounds__(256) void k_spatial(
    const short* __restrict__ XB, const short* __restrict__ attnB, const short* __restrict__ wb,
    const float* __restrict__ b_out, const float* __restrict__ bn_out,
    const float* __restrict__ b_ff,  const float* __restrict__ bn_ff,
    short* __restrict__ Y)
{
    const int n = blockIdx.x >> 5, tc = blockIdx.x & 31, t0 = tc*4;
    const int tid = threadIdx.x;
    const int w = tid>>6, lane = tid&63, lr = lane&15, lq = lane>>4;
    __shared__ short xs[4][32][72];
    __shared__ short wlo[64][200];
    __shared__ short wlf[64][72];
    __shared__ short ab[32][104];
    __shared__ short gsT[4][64][104];
    __shared__ short y1[4][32][72];
    __shared__ float sc1s[64], sh1s[64], sc2s[64], sh2s[64];

    for (int i = tid; i < 4*32*8; i += 256) {
        const int row = i>>3, seg = i&7, tl = row>>5, uv = row&31;
        bf8 val = {0,0,0,0,0,0,0,0};
        if (uv < 25) val = *(const bf8*)&XB[((size_t)n*3200 + (t0+tl)*25 + uv)*64 + seg*8];
        *(bf8*)&xs[tl][uv][seg*8] = val;
    }
    for (int i = tid; i < 64*24; i += 256) {
        const int o = i/24, seg = i%24;
        *(bf8*)&wlo[o][seg*8] = *(const bf8*)&wb[6144 + o*192 + seg*8];
    }
    for (int i = tid; i < 64*8; i += 256) {
        const int o = i>>3, seg = i&7;
        *(bf8*)&wlf[o][seg*8] = *(const bf8*)&wb[18432 + o*64 + seg*8];
    }
    for (int i = tid; i < 32*12; i += 256) {
        const int v = i/12, seg = i%12;
        *(bf8*)&ab[v][seg*8] = *(const bf8*)&attnB[(size_t)n*3072 + v*96 + seg*8];
    }
    if (tid < 64) {
        float g=bn_out[tid], bb=bn_out[64+tid], m=bn_out[128+tid], vv=bn_out[192+tid];
        float inv = g*rsqrtf(vv+BN_EPS);
        sc1s[tid]=inv; sh1s[tid]=(b_out[tid]-m)*inv+bb;
        g=bn_ff[tid]; bb=bn_ff[64+tid]; m=bn_ff[128+tid]; vv=bn_ff[192+tid];
        inv = g*rsqrtf(vv+BN_EPS);
        sc2s[tid]=inv; sh2s[tid]=(b_ff[tid]-m)*inv+bb;
    }
    __syncthreads();

    const int t = t0 + w;
    for (int s = 0; s < 3; ++s) {
        for (int mt = 0; mt < 2; ++mt) {
            const bf8 a0 = *(const bf8*)&xs[w][mt*16+lr][lq*8];
            const bf8 a1 = *(const bf8*)&xs[w][mt*16+lr][32+lq*8];
            for (int nt = 0; nt < 4; ++nt) {
                f4 acc = {0.f,0.f,0.f,0.f};
                const bf8 b0 = *(const bf8*)&wlo[nt*16+lr][s*64 + lq*8];
                const bf8 b1 = *(const bf8*)&wlo[nt*16+lr][s*64 + 32 + lq*8];
                acc = MFMA(a0,b0,acc); acc = MFMA(a1,b1,acc);
                const int o = nt*16+lr, u0 = mt*16+lq*4;
                *(s4*)&gsT[w][o][s*32+u0] = packf4(acc.x,acc.y,acc.z,acc.w);
            }
        }
    }
    for (int mt = 0; mt < 4; ++mt) {
        const bf8 a0 = *(const bf8*)&gsT[w][mt*16+lr][lq*8];
        const bf8 a1 = *(const bf8*)&gsT[w][mt*16+lr][32+lq*8];
        const bf8 a2 = *(const bf8*)&gsT[w][mt*16+lr][64+lq*8];
        for (int nt = 0; nt < 2; ++nt) {
            f4 acc = {0.f,0.f,0.f,0.f};
            const bf8 b0 = *(const bf8*)&ab[nt*16+lr][lq*8];
            const bf8 b1 = *(const bf8*)&ab[nt*16+lr][32+lq*8];
            const bf8 b2 = *(const bf8*)&ab[nt*16+lr][64+lq*8];
            acc = MFMA(a0,b0,acc); acc = MFMA(a1,b1,acc); acc = MFMA(a2,b2,acc);
            const int v = nt*16+lr, o0 = mt*16+lq*4;
            const s4 xr = *(const s4*)&xs[w][v][o0];
            const float r0 = lrelu(acc.x*sc1s[o0  ]+sh1s[o0  ]+b2f(xr.x));
            const float r1 = lrelu(acc.y*sc1s[o0+1]+sh1s[o0+1]+b2f(xr.y));
            const float r2 = lrelu(acc.z*sc1s[o0+2]+sh1s[o0+2]+b2f(xr.z));
            const float r3 = lrelu(acc.w*sc1s[o0+3]+sh1s[o0+3]+b2f(xr.w));
            *(s4*)&y1[w][v][o0] = packf4(r0,r1,r2,r3);
        }
    }
    for (int mt = 0; mt < 4; ++mt) {
        const bf8 a0 = *(const bf8*)&wlf[mt*16+lr][lq*8];
        const bf8 a1 = *(const bf8*)&wlf[mt*16+lr][32+lq*8];
        for (int nt = 0; nt < 2; ++nt) {
            f4 acc = {0.f,0.f,0.f,0.f};
            const bf8 b0 = *(const bf8*)&y1[w][nt*16+lr][lq*8];
            const bf8 b1 = *(const bf8*)&y1[w][nt*16+lr][32+lq*8];
            acc = MFMA(a0,b0,acc); acc = MFMA(a1,b1,acc);
            const int v = nt*16+lr, o0 = mt*16+lq*4;
            if (v < 25) {
                const s4 xr = *(const s4*)&xs[w][v][o0];
                const float r0 = lrelu(acc.x*sc2s[o0  ]+sh2s[o0  ]+b2f(xr.x));
                const float r1 = lrelu(acc.y*sc2s[o0+1]+sh2s[o0+1]+b2f(xr.y));
                const float r2 = lrelu(acc.z*sc2s[o0+2]+sh2s[o0+2]+b2f(xr.z));
                const float r3 = lrelu(acc.w*sc2s[o0+3]+sh2s[o0+3]+b2f(xr.w));
                *(s4*)&Y[((size_t)n*3200 + t*25 + v)*64 + o0] = packf4(r0,r1,r2,r3);
            }
        }
    }
}

// temporal q/k proj -> QKT bf16 [n][t][128oc][25v]
__global__ __launch_bounds__(256) void k_qkt(
    const short* __restrict__ Y, const short* __restrict__ wb,
    const float* __restrict__ b_in_t, short* __restrict__ qkt)
{
    const int n = blockIdx.x >> 5, tc = blockIdx.x & 31, t0 = tc*4;
    const int tid = threadIdx.x;
    const int w = tid>>6, lane = tid&63, lr = lane&15, lq = lane>>4;
    __shared__ short ys[4][32][72];
    __shared__ short wi[128][72];
    for (int i = tid; i < 4*32*8; i += 256) {
        const int row = i>>3, seg = i&7, tl = row>>5, v = row&31;
        bf8 val = {0,0,0,0,0,0,0,0};
        if (v < 25) val = *(const bf8*)&Y[((size_t)n*3200 + (t0+tl)*25 + v)*64 + seg*8];
        *(bf8*)&ys[tl][v][seg*8] = val;
    }
    for (int i = tid; i < 128*8; i += 256) {
        const int o = i>>3, seg = i&7;
        *(bf8*)&wi[o][seg*8] = *(const bf8*)&wb[22528 + o*64 + seg*8];
    }
    __syncthreads();
    for (int mi = 0; mi < 2; ++mi) {
        const int mt = w*2+mi, tl = mt>>1, vh = mt&1;
        const bf8 a0 = *(const bf8*)&ys[tl][vh*16+lr][lq*8];
        const bf8 a1 = *(const bf8*)&ys[tl][vh*16+lr][32+lq*8];
        for (int nt = 0; nt < 8; ++nt) {
            f4 acc = {0.f,0.f,0.f,0.f};
            const bf8 b0 = *(const bf8*)&wi[nt*16+lr][lq*8];
            const bf8 b1 = *(const bf8*)&wi[nt*16+lr][32+lq*8];
            acc = MFMA(a0,b0,acc); acc = MFMA(a1,b1,acc);
            const int oc = nt*16+lr, v0 = vh*16+lq*4, t = t0+tl;
            const float bias = b_in_t[oc];
            const size_t base = (size_t)n*409600 + (size_t)t*3200 + oc*25 + v0;
            if (v0 < 24)
                *(s4*)&qkt[base] = packf4(acc.x+bias, acc.y+bias, acc.z+bias, acc.w+bias);
            else if (v0 == 24)
                qkt[base] = f2bs(acc.x+bias);
        }
    }
}

// temporal scores -> aT bf16 [n][ds][q][t] (zeros in masked region)
__global__ __launch_bounds__(256) void k_score_t(
    const short* __restrict__ qkt, const float* __restrict__ alphat_f,
    const float* __restrict__ alphat_b, short* __restrict__ aT)
{
    const int n = blockIdx.x >> 2, ds = blockIdx.x & 3, dir = ds>>1, s = ds&1;
    const int qoff = dir*32 + s*16, koff = 64 + dir*32 + s*16;
    const float alpha = dir ? alphat_b[s] : alphat_f[s];
    const int tid = threadIdx.x, w = tid>>6, lane = tid&63, lr = lane&15, lq = lane>>4;
    const short* qb = qkt + (size_t)n*409600;
    short* ao = aT + (size_t)(n*4+ds)*16384;
    const bf8 zf = {0,0,0,0,0,0,0,0};
    for (int ni = 0; ni < 2; ++ni) {
        const int nt = w*2+ni;
        for (int mt = 0; mt < 8; ++mt) {
            const int q = nt*16+lr, t0r = mt*16+lq*4;
            const bool skip = (dir==0) ? (mt < nt) : (mt > nt);
            if (skip) { s4 z = {0,0,0,0}; *(s4*)&ao[q*128 + t0r] = z; continue; }
            f4 acc = {0.f,0.f,0.f,0.f};
            for (int ks = 0; ks < 13; ++ks) {
                bf8 af, bf;
                if (ks==12 && lq>=2) { af = zf; bf = zf; }
                else {
                    af = *(const bf8*)&qb[(size_t)(mt*16+lr)*3200 + qoff*25 + ks*32 + lq*8];
                    bf = *(const bf8*)&qb[(size_t)(nt*16+lr)*3200 + koff*25 + ks*32 + lq*8];
                }
                acc = MFMA(af, bf, acc);
            }
            float r[4];
            #pragma unroll
            for (int j = 0; j < 4; ++j) {
                const int tt = t0r + j;
                const bool ok = (dir==0) ? (tt >= q) : (tt <= q);
                const float a = (j==0)?acc.x:((j==1)?acc.y:((j==2)?acc.z:acc.w));
                r[j] = ok ? tanhf(a*(1.f/400.f))*alpha : 0.f;
            }
            *(s4*)&ao[q*128 + t0r] = packf4(r[0],r[1],r[2],r[3]);
        }
    }
}

// ---------------------------------------------------------------------------
// Fused temporal aggregation. block = (n, v), 4 waves; wave w owns o-tile w.
// ---------------------------------------------------------------------------
__global__ __launch_bounds__(256) void k_tagg(
    const short* __restrict__ Y, const short* __restrict__ wb,
    const short* __restrict__ aT, short* __restrict__ U)
{
    const int n = blockIdx.x / 25, v = blockIdx.x % 25;
    const int tid = threadIdx.x, w = tid>>6, lane = tid&63, lr = lane&15, lq = lane>>4;
    __shared__ short ys[128][72];     // Y[t][c] for this v      18.4 KB
    __shared__ short wolds[64][72];   // w_out_t slice [o][64c]   9.2 KB
    __shared__ short pt[64][136];     // PTl [o][t]              17.4 KB
    __shared__ short ats[128][136];   // aT[ds] [q][t]           34.8 KB

    for (int i = tid; i < 128*8; i += 256) {
        const int t = i>>3, seg = i&7;
        *(bf8*)&ys[t][seg*8] = *(const bf8*)&Y[((size_t)n*3200 + t*25 + v)*64 + seg*8];
    }

    f4 acc[8];
    #pragma unroll
    for (int nt = 0; nt < 8; ++nt) { acc[nt].x=0.f; acc[nt].y=0.f; acc[nt].z=0.f; acc[nt].w=0.f; }

    for (int ds = 0; ds < 4; ++ds) {
        const int dir = ds>>1;
        __syncthreads();   // prev-ds pt/ats reads complete (and ys staged, iter 0)
        for (int i = tid; i < 64*8; i += 256) {
            const int o = i>>3, seg = i&7;
            *(bf8*)&wolds[o][seg*8] = *(const bf8*)&wb[30720 + o*256 + ds*64 + seg*8];
        }
        for (int i = tid; i < 128*16; i += 256) {
            const int q = i>>4, seg = i&15;
            *(bf8*)&ats[q][seg*8] = *(const bf8*)&aT[(size_t)(n*4+ds)*16384 + q*128 + seg*8];
        }
        __syncthreads();
        // PTl: A = ys (t rows), B = wolds (o rows) -> D[t][o];
        {
            const bf8 b0 = *(const bf8*)&wolds[w*16+lr][lq*8];
            const bf8 b1 = *(const bf8*)&wolds[w*16+lr][32+lq*8];
            #pragma unroll
            for (int tt = 0; tt < 8; ++tt) {
                f4 p = {0.f,0.f,0.f,0.f};
                const bf8 a0 = *(const bf8*)&ys[tt*16+lr][lq*8];
                const bf8 a1 = *(const bf8*)&ys[tt*16+lr][32+lq*8];
                p = MFMA(a0,b0,p); p = MFMA(a1,b1,p);
                *(s4*)&pt[w*16+lr][tt*16+lq*4] = packf4(p.x,p.y,p.z,p.w);
            }
        }
        __syncthreads();
        // U accumulate: A = pt (o rows), B = ats (q rows) -> D[o][q]
        bf8 af[4];
        #pragma unroll
        for (int ks = 0; ks < 4; ++ks)
            af[ks] = *(const bf8*)&pt[w*16+lr][ks*32+lq*8];
        #pragma unroll
        for (int nt = 0; nt < 8; ++nt) {
            #pragma unroll
            for (int ks = 0; ks < 4; ++ks) {
                const bool skip = (dir==0) ? (ks*32+31 < nt*16) : (ks*32 > nt*16+15);
                if (skip) continue;
                const bf8 bf = *(const bf8*)&ats[nt*16+lr][ks*32+lq*8];
                acc[nt] = MFMA(af[ks], bf, acc[nt]);
            }
        }
    }
    // write U[q][v][o] once
    #pragma unroll
    for (int nt = 0; nt < 8; ++nt) {
        const int q = nt*16+lr, o0 = w*16+lq*4;
        *(s4*)&U[((size_t)(n*128+q)*25 + v)*64 + o0] =
            packf4(acc[nt].x, acc[nt].y, acc[nt].z, acc[nt].w);
    }
}

// temporal ff block: z1 = lrelu(y + u*sc1+sh1); Y = lrelu(y + BN(Wff@z1)) in-place
__global__ __launch_bounds__(256) void k_temporal(
    const short* __restrict__ U, short* __restrict__ Y, const short* __restrict__ wb,
    const float* __restrict__ b_out, const float* __restrict__ bn_out,
    const float* __restrict__ b_ff,  const float* __restrict__ bn_ff)
{
    const int n = blockIdx.x >> 5, qc = blockIdx.x & 31, q0 = qc*4;
    const int tid = threadIdx.x, w = tid>>6, lane = tid&63, lr = lane&15, lq = lane>>4;
    __shared__ short zs[112][72];
    __shared__ short z1[112][72];
    __shared__ short zout[112][72];
    __shared__ short wf[64][72];
    __shared__ float sc1s[64], sh1s[64], sc2s[64], sh2s[64];
    if (tid < 64) {
        float g=bn_out[tid], bb=bn_out[64+tid], m=bn_out[128+tid], vv=bn_out[192+tid];
        float inv = g*rsqrtf(vv+BN_EPS);
        sc1s[tid]=inv; sh1s[tid]=(b_out[tid]-m)*inv+bb;
        g=bn_ff[tid]; bb=bn_ff[64+tid]; m=bn_ff[128+tid]; vv=bn_ff[192+tid];
        inv = g*rsqrtf(vv+BN_EPS);
        sc2s[tid]=inv; sh2s[tid]=(b_ff[tid]-m)*inv+bb;
    }
    for (int i = tid; i < 64*8; i += 256) {
        const int o = i>>3, seg = i&7;
        *(bf8*)&wf[o][seg*8] = *(const bf8*)&wb[47104 + o*64 + seg*8];
    }
    __syncthreads();
    for (int i = tid; i < 112*8; i += 256) {
        const int row = i>>3, seg = i&7;
        bf8 yv = {0,0,0,0,0,0,0,0}, zv = yv;
        if (row < 100) {
            const int q = q0 + row/25, v = row%25;
            yv = *(const bf8*)&Y[((size_t)n*3200 + q*25 + v)*64 + seg*8];
            const bf8 uv = *(const bf8*)&U[((size_t)(n*128+q)*25 + v)*64 + seg*8];
            #pragma unroll
            for (int j = 0; j < 8; ++j) {
                const int o = seg*8+j;
                zv[j] = f2bs(lrelu(b2f(yv[j]) + b2f(uv[j])*sc1s[o] + sh1s[o]));
            }
        }
        *(bf8*)&zs[row][seg*8] = yv;
        *(bf8*)&z1[row][seg*8] = zv;
    }
    __syncthreads();
    const bf8 a0 = *(const bf8*)&wf[w*16+lr][lq*8];
    const bf8 a1 = *(const bf8*)&wf[w*16+lr][32+lq*8];
    for (int nt = 0; nt < 7; ++nt) {
        f4 acc = {0.f,0.f,0.f,0.f};
        const bf8 b0 = *(const bf8*)&z1[nt*16+lr][lq*8];
        const bf8 b1 = *(const bf8*)&z1[nt*16+lr][32+lq*8];
        acc = MFMA(a0,b0,acc); acc = MFMA(a1,b1,acc);
        const int px = nt*16+lr, o0 = w*16+lq*4;
        const s4 yr = *(const s4*)&zs[px][o0];
        const float r0 = lrelu(acc.x*sc2s[o0  ]+sh2s[o0  ]+b2f(yr.x));
        const float r1 = lrelu(acc.y*sc2s[o0+1]+sh2s[o0+1]+b2f(yr.y));
        const float r2 = lrelu(acc.z*sc2s[o0+2]+sh2s[o0+2]+b2f(yr.z));
        const float r3 = lrelu(acc.w*sc2s[o0+3]+sh2s[o0+3]+b2f(yr.w));
        *(s4*)&zout[px][o0] = packf4(r0,r1,r2,r3);
    }
    __syncthreads();
    for (int i = tid; i < 100*8; i += 256) {
        const int row = i>>3, seg = i&7;
        *(bf8*)&Y[((size_t)n*3200 + q0*25 + row)*64 + seg*8] = *(const bf8*)&zout[row][seg*8];
    }
}

// ---------------------------------------------------------------------------
// tcn v3: out[o][t][v] = lrelu(BN(sum_{dt,c} w[o][c][dt]*z[t+dt-3,v,c]+b)+z)
// Weights af[2][14] in regs (AGPR-backed); bfr[14] hoisted per nn; 8
// accumulators (2mt x 4 chains) interleaved -> dep-reuse distance 8.
// yout LDS round-trip REMOVED: MFMA D-layout gives lane (col=px, rows=4
// consecutive o) -> direct global_store_dword = 4x64B coalesced segments.
// LDS = zs only (50.7 KB). Conflicts (yout was the source) ~eliminated.
// ---------------------------------------------------------------------------
__global__ __launch_bounds__(256, 2) void k_tcn(
    const short* __restrict__ Y, const short* __restrict__ wb,
    const float* __restrict__ b, const float* __restrict__ bn,
    float* __restrict__ out)
{
    const int n = blockIdx.x >> 5, tc = (blockIdx.x >> 1) & 15, oh = blockIdx.x & 1;
    const int t0 = tc*8;
    const int tid = threadIdx.x, w = tid>>6, lane = tid&63, lr = lane&15, lq = lane>>4;
    __shared__ short zs[352][72];
    __shared__ float scs[32], shs[32];

    // weights -> registers (issued first; overlap LDS staging below)
    bf8 af[2][14];
    #pragma unroll
    for (int mt = 0; mt < 2; ++mt)
        #pragma unroll
        for (int st = 0; st < 14; ++st)
            af[mt][st] = *(const bf8*)&wb[51200 + (oh*32 + mt*16 + lr)*448 + st*32 + lq*8];

    if (tid < 32) {
        const int o = oh*32 + tid;
        const float g=bn[o], bb=bn[64+o], m=bn[128+o], vv=bn[192+o];
        const float inv = g*rsqrtf(vv+BN_EPS);
        scs[tid]=inv; shs[tid]=(b[o]-m)*inv+bb;
    }
    for (int i = tid; i < 352*8; i += 256) {
        const int row = i>>3, seg = i&7;
        bf8 val = {0,0,0,0,0,0,0,0};
        if (row < 350) {
            const int tlp = row/25, v = row%25, t = t0 - 3 + tlp;
            if (t >= 0 && t < 128)
                val = *(const bf8*)&Y[((size_t)n*3200 + t*25 + v)*64 + seg*8];
        }
        *(bf8*)&zs[row][seg*8] = val;
    }
    __syncthreads();
    for (int nn = 0; nn < 4; ++nn) {
        const int nt = w + nn*4;
        if (nt >= 13) break;
        // pixel fragments for this nt, shared by both mt
        bf8 bfr[14];
        #pragma unroll
        for (int st = 0; st < 14; ++st)
            bfr[st] = *(const bf8*)&zs[nt*16 + lr + (st>>1)*25][(st&1)*32 + lq*8];
        // 28 MFMA, 8 accumulators interleaved
        f4 ac[2][4];
        #pragma unroll
        for (int m2 = 0; m2 < 2; ++m2)
            #pragma unroll
            for (int j = 0; j < 4; ++j) { ac[m2][j].x=0.f; ac[m2][j].y=0.f; ac[m2][j].z=0.f; ac[m2][j].w=0.f; }
        #pragma unroll
        for (int st = 0; st < 14; ++st) {
            ac[0][st&3] = MFMA(af[0][st], bfr[st], ac[0][st&3]);
            ac[1][st&3] = MFMA(af[1][st], bfr[st], ac[1][st&3]);
        }
        const int px = nt*16+lr;
        if (px < 200) {
            #pragma unroll
            for (int mt = 0; mt < 2; ++mt) {
                const float ax = ac[mt][0].x+ac[mt][1].x+ac[mt][2].x+ac[mt][3].x;
                const float ay = ac[mt][0].y+ac[mt][1].y+ac[mt][2].y+ac[mt][3].y;
                const float az = ac[mt][0].z+ac[mt][1].z+ac[mt][2].z+ac[mt][3].z;
                const float aw = ac[mt][0].w+ac[mt][1].w+ac[mt][2].w+ac[mt][3].w;
                const int o0l = mt*16+lq*4;
                const s4 zr = *(const s4*)&zs[px+75][oh*32+o0l];
                float* ob = out + (size_t)n*204800 + (size_t)(oh*32+o0l)*3200 + t0*25 + px;
                ob[0]    = lrelu(ax*scs[o0l  ]+shs[o0l  ]+b2f(zr.x));
                ob[3200] = lrelu(ay*scs[o0l+1]+shs[o0l+1]+b2f(zr.y));
                ob[6400] = lrelu(az*scs[o0l+2]+shs[o0l+2]+b2f(zr.z));
                ob[9600] = lrelu(aw*scs[o0l+3]+shs[o0l+3]+b2f(zr.w));
            }
        }
    }
}

// ---------------------------------------------------------------------------
extern "C" void kernel_launch(void* const* d_in, const int* in_sizes, int n_in,
                              void* d_out, int out_size, void* d_ws, size_t ws_size,
                              hipStream_t stream) {
    const float* x        = (const float*)d_in[0];
    const float* w_in_s   = (const float*)d_in[1];
    const float* b_in_s   = (const float*)d_in[2];
    const float* alphas   = (const float*)d_in[3];
    const float* att0s    = (const float*)d_in[4];
    const float* w_out_s  = (const float*)d_in[5];
    const float* b_out_s  = (const float*)d_in[6];
    const float* bn_out_s = (const float*)d_in[7];
    const float* w_ff_s   = (const float*)d_in[8];
    const float* b_ff_s   = (const float*)d_in[9];
    const float* bn_ff_s  = (const float*)d_in[10];
    const float* w_in_t   = (const float*)d_in[11];
    const float* b_in_t   = (const float*)d_in[12];
    const float* alphat_f = (const float*)d_in[13];
    const float* alphat_b = (const float*)d_in[14];
    const float* w_out_t  = (const float*)d_in[15];
    const float* b_out_t  = (const float*)d_in[16];
    const float* bn_out_t = (const float*)d_in[17];
    const float* w_ff_t   = (const float*)d_in[18];
    const float* b_ff_t   = (const float*)d_in[19];
    const float* bn_ff_t  = (const float*)d_in[20];
    const float* w_tcn    = (const float*)d_in[21];
    const float* b_tcn    = (const float*)d_in[22];
    const float* bn_tcn   = (const float*)d_in[23];
    float* out = (float*)d_out;
    char* ws = (char*)d_ws;

    short* wb    = (short*)(ws + 0);
    short* attnB = (short*)(ws + 4102144);
    short* Y     = (short*)(ws + 4888576);
    short* aT    = (short*)(ws + 57317376);
    short* XB    = (short*)(ws + 74094592);           // phase 1
    short* QKT   = (short*)(ws + 74094592);           // phase 2 (XB dead)
    short* U     = (short*)(ws + 74094592 + 52428800);

    k_prep<<<64, 256, 0, stream>>>(w_in_s, w_out_s, w_ff_s, w_in_t, w_out_t, w_ff_t, w_tcn, wb);
    k_x2b<<<2048, 256, 0, stream>>>(x, XB);
    k_attn_s<<<NN * 3, 256, 0, stream>>>(XB, wb, b_in_s, alphas, att0s, attnB);
    k_spatial<<<4096, 256, 0, stream>>>(XB, attnB, wb, b_out_s, bn_out_s, b_ff_s, bn_ff_s, Y);
    k_qkt<<<4096, 256, 0, stream>>>(Y, wb, b_in_t, QKT);
    k_score_t<<<512, 256, 0, stream>>>(QKT, alphat_f, alphat_b, aT);
    k_tagg<<<NN * 25, 256, 0, stream>>>(Y, wb, aT, U);
    k_temporal<<<4096, 256, 0, stream>>>(U, Y, wb, b_out_t, bn_out_t, b_ff_t, bn_ff_t);
    k_tcn<<<4096, 256, 0, stream>>>(Y, wb, b_tcn, bn_tcn, out);
}

// Round 4
// 714.726 us; speedup vs baseline: 1.1651x; 1.0773x over previous
//
#include <hip/hip_runtime.h>
#include <math.h>

#define NN   128
#define TTc  128
#define VVc  25
#define TV   3200
#define BN_EPS 1e-5f

typedef __attribute__((ext_vector_type(8))) short bf8;   // 8 bf16 in 4 VGPRs
typedef __attribute__((ext_vector_type(4))) short s4;    // 4 bf16 (b64)
typedef __attribute__((ext_vector_type(4))) float f4;    // MFMA accumulator

#define MFMA(a,b,c) __builtin_amdgcn_mfma_f32_16x16x32_bf16(a,b,c,0,0,0)

__device__ __forceinline__ float lrelu(float a){ return a>=0.f ? a : 0.1f*a; }
__device__ __forceinline__ short f2bs(float f){
    union{float f; unsigned u;} x; x.f = f;
    unsigned r = x.u + 0x7FFF + ((x.u>>16)&1);
    return (short)(r>>16);
}
__device__ __forceinline__ float b2f(short s){
    union{unsigned u; float f;} x; x.u = ((unsigned)(unsigned short)s)<<16; return x.f;
}
__device__ __forceinline__ s4 packf4(float a,float b,float c,float d){
    s4 r; r.x=f2bs(a); r.y=f2bs(b); r.z=f2bs(c); r.w=f2bs(d); return r;
}

// ---------------------------------------------------------------------------
// Workspace layout (total 178,952,192 B, proven OK):
//  wb bf16 weights       : byte 0
//  attnB bf16 [n][32v][96]: byte 4102144
//  Y  bf16 [n][3200][64] : byte 4888576
//  aT bf16 [n][4][q][t]  : byte 57317376
//  R  : byte 74094592 : XB -> QKT
//  U  : byte 74094592+52428800
// wb element offsets: w_in_s 0 [96][64]; w_out_s 6144 [64][192]; w_ff_s 18432
//  [64][64]; w_in_t 22528 [128][64]; w_out_t 30720 [64][256]; w_ff_t 47104
//  [64][64]; wt 51200 [64][448] (o, dt*64+c)
// ---------------------------------------------------------------------------

__global__ __launch_bounds__(256) void k_prep(
    const float* __restrict__ w_in_s, const float* __restrict__ w_out_s,
    const float* __restrict__ w_ff_s, const float* __restrict__ w_in_t,
    const float* __restrict__ w_out_t, const float* __restrict__ w_ff_t,
    const float* __restrict__ w_tcn, short* __restrict__ wb)
{
    const int total = 51200 + 64*448;
    for (int i = blockIdx.x*256 + threadIdx.x; i < total; i += gridDim.x*256) {
        float v;
        if      (i < 6144)  v = w_in_s[i];
        else if (i < 18432) v = w_out_s[i-6144];
        else if (i < 22528) v = w_ff_s[i-18432];
        else if (i < 30720) v = w_in_t[i-22528];
        else if (i < 47104) v = w_out_t[i-30720];
        else if (i < 51200) v = w_ff_t[i-47104];
        else { int j=i-51200; int o=j/448; int r=j%448; int dt=r>>6; int c=r&63;
               v = w_tcn[(o*64+c)*7 + dt]; }
        wb[i] = f2bs(v);
    }
}

// x f32 [n][c][t][v] -> XB bf16 pixel-major [n][t*25+v][64]
// [203] pad: lane stride 4 rows = 812 dw == 12 mod 32 -> 2-way (free).
__global__ __launch_bounds__(256) void k_x2b(const float* __restrict__ x, short* __restrict__ XB)
{
    const int n = blockIdx.x >> 4, tc = blockIdx.x & 15, t0 = tc*8;
    const int tid = threadIdx.x;
    __shared__ float xs[64][203];
    const float* xb = x + (size_t)n*204800 + t0*25;
    for (int i = tid; i < 64*200; i += 256) { int c=i/200, p=i%200; xs[c][p] = xb[(size_t)c*3200 + p]; }
    __syncthreads();
    short* ob = XB + (size_t)n*204800 + t0*25*64;
    for (int i = tid; i < 200*16; i += 256) {
        const int p = i>>4, c0 = (i&15)<<2;
        *(s4*)&ob[p*64 + c0] = packf4(xs[c0][p], xs[c0+1][p], xs[c0+2][p], xs[c0+3][p]);
    }
}

// ---------------------------------------------------------------------------
// Fused spatial attention scores (MFMA). grid = N*SS, 4 waves.
// ---------------------------------------------------------------------------
__global__ __launch_bounds__(256) void k_attn_s(
    const short* __restrict__ XB, const short* __restrict__ wb,
    const float* __restrict__ b_in_s, const float* __restrict__ alphas,
    const float* __restrict__ att0s, short* __restrict__ attnB)
{
    const int n = blockIdx.x / 3, s = blockIdx.x % 3;
    const int tid = threadIdx.x, w = tid>>6, lane = tid&63, lr = lane&15, lq = lane>>4;
    __shared__ short ys[208][72];     // staged pixels [px][64c]
    __shared__ short qkl[208][40];    // projected [px][32ch]: 0-15 q, 16-31 k
    __shared__ short wsl[32][72];     // weight rows (q 16 + k 16) x 64c
    __shared__ float bl[32];

    for (int i = tid; i < 32*8; i += 256) {
        const int cl = i>>3, seg = i&7;
        const int row = (cl < 16) ? (s*16 + cl) : (48 + s*16 + (cl-16));
        *(bf8*)&wsl[cl][seg*8] = *(const bf8*)&wb[row*64 + seg*8];
    }
    if (tid < 32) {
        const int row = (tid < 16) ? (s*16 + tid) : (48 + s*16 + (tid-16));
        bl[tid] = b_in_s[row];
    }

    const int mt = w>>1, sn = w&1;     // this wave's score tile (u-tile, v-tile)
    f4 acc = {0.f,0.f,0.f,0.f};

    for (int ch = 0; ch < 16; ++ch) {
        __syncthreads();   // qkl/ys from prev iter fully consumed
        for (int i = tid; i < 208*8; i += 256) {
            const int row = i>>3, seg = i&7;
            bf8 val = {0,0,0,0,0,0,0,0};
            if (row < 200)
                val = *(const bf8*)&XB[((size_t)n*3200 + ch*200 + row)*64 + seg*8];
            *(bf8*)&ys[row][seg*8] = val;
        }
        __syncthreads();
        // projection: wave w covers px-tiles {w, w+4, w+8, w+12}
        for (int nn = 0; nn < 4; ++nn) {
            const int nt2 = w + nn*4;
            if (nt2 >= 13) break;
            const bf8 b0 = *(const bf8*)&ys[nt2*16+lr][lq*8];
            const bf8 b1 = *(const bf8*)&ys[nt2*16+lr][32+lq*8];
            for (int mt2 = 0; mt2 < 2; ++mt2) {
                f4 pa = {0.f,0.f,0.f,0.f};
                const bf8 a0 = *(const bf8*)&wsl[mt2*16+lr][lq*8];
                const bf8 a1 = *(const bf8*)&wsl[mt2*16+lr][32+lq*8];
                pa = MFMA(a0,b0,pa); pa = MFMA(a1,b1,pa);
                const int px = nt2*16+lr, c0 = mt2*16+lq*4;
                *(s4*)&qkl[px][c0] =
                    packf4(pa.x+bl[c0], pa.y+bl[c0+1], pa.z+bl[c0+2], pa.w+bl[c0+3]);
            }
        }
        __syncthreads();
        // score accumulate: k = (t_local, c), 4 steps of 32
        for (int ks = 0; ks < 4; ++ks) {
            const int tl = ks*2 + (lq>>1);
            const bf8 af = *(const bf8*)&qkl[tl*25 + mt*16+lr][(lq&1)*8];
            const bf8 bf = *(const bf8*)&qkl[tl*25 + sn*16+lr][16 + (lq&1)*8];
            acc = MFMA(af, bf, acc);
        }
    }
    const float alpha = alphas[s];
    const int v = sn*16 + lr, u0 = mt*16 + lq*4;
    float r[4];
    #pragma unroll
    for (int j = 0; j < 4; ++j) {
        const int u = u0 + j;
        const float a = (j==0)?acc.x:((j==1)?acc.y:((j==2)?acc.z:acc.w));
        r[j] = (u < 25 && v < 25)
             ? tanhf(a*(1.f/2048.f))*alpha + att0s[s*625 + u*25 + v] : 0.f;
    }
    *(s4*)&attnB[(size_t)n*3072 + v*96 + s*32 + u0] = packf4(r[0],r[1],r[2],r[3]);
}

// ---------------------------------------------------------------------------
// fused spatial block (MFMA). block=(n, t-chunk4), wave w owns t=t0+w.
// ---------------------------------------------------------------------------
__global__ __launch_bounds__(256) void k_spatial(
    const short* __restrict__ XB, const short* __restrict__ attnB, const short* __restrict__ wb,
    const float* __restrict__ b_out, const float* __restrict__ bn_out,
    const float* __restrict__ b_ff,  const float* __restrict__ bn_ff,
    short* __restrict__ Y)
{
    const int n = blockIdx.x >> 5, tc = blockIdx.x & 31, t0 = tc*4;
    const int tid = threadIdx.x;
    const int w = tid>>6, lane = tid&63, lr = lane&15, lq = lane>>4;
    __shared__ short xs[4][32][72];
    __shared__ short wlo[64][200];
    __shared__ short wlf[64][72];
    __shared__ short ab[32][104];
    __shared__ short gsT[4][64][104];
    __shared__ short y1[4][32][72];
    __shared__ float sc1s[64], sh1s[64], sc2s[64], sh2s[64];

    for (int i = tid; i < 4*32*8; i += 256) {
        const int row = i>>3, seg = i&7, tl = row>>5, uv = row&31;
        bf8 val = {0,0,0,0,0,0,0,0};
        if (uv < 25) val = *(const bf8*)&XB[((size_t)n*3200 + (t0+tl)*25 + uv)*64 + seg*8];
        *(bf8*)&xs[tl][uv][seg*8] = val;
    }
    for (int i = tid; i < 64*24; i += 256) {
        const int o = i/24, seg = i%24;
        *(bf8*)&wlo[o][seg*8] = *(const bf8*)&wb[6144 + o*192 + seg*8];
    }
    for (int i = tid; i < 64*8; i += 256) {
        const int o = i>>3, seg = i&7;
        *(bf8*)&wlf[o][seg*8] = *(const bf8*)&wb[18432 + o*64 + seg*8];
    }
    for (int i = tid; i < 32*12; i += 256) {
        const int v = i/12, seg = i%12;
        *(bf8*)&ab[v][seg*8] = *(const bf8*)&attnB[(size_t)n*3072 + v*96 + seg*8];
    }
    if (tid < 64) {
        float g=bn_out[tid], bb=bn_out[64+tid], m=bn_out[128+tid], vv=bn_out[192+tid];
        float inv = g*rsqrtf(vv+BN_EPS);
        sc1s[tid]=inv; sh1s[tid]=(b_out[tid]-m)*inv+bb;
        g=bn_ff[tid]; bb=bn_ff[64+tid]; m=bn_ff[128+tid]; vv=bn_ff[192+tid];
        inv = g*rsqrtf(vv+BN_EPS);
        sc2s[tid]=inv; sh2s[tid]=(b_ff[tid]-m)*inv+bb;
    }
    __syncthreads();

    const int t = t0 + w;
    for (int s = 0; s < 3; ++s) {
        for (int mt = 0; mt < 2; ++mt) {
            const bf8 a0 = *(const bf8*)&xs[w][mt*16+lr][lq*8];
            const bf8 a1 = *(const bf8*)&xs[w][mt*16+lr][32+lq*8];
            for (int nt = 0; nt < 4; ++nt) {
                f4 acc = {0.f,0.f,0.f,0.f};
                const bf8 b0 = *(const bf8*)&wlo[nt*16+lr][s*64 + lq*8];
                const bf8 b1 = *(const bf8*)&wlo[nt*16+lr][s*64 + 32 + lq*8];
                acc = MFMA(a0,b0,acc); acc = MFMA(a1,b1,acc);
                const int o = nt*16+lr, u0 = mt*16+lq*4;
                *(s4*)&gsT[w][o][s*32+u0] = packf4(acc.x,acc.y,acc.z,acc.w);
            }
        }
    }
    for (int mt = 0; mt < 4; ++mt) {
        const bf8 a0 = *(const bf8*)&gsT[w][mt*16+lr][lq*8];
        const bf8 a1 = *(const bf8*)&gsT[w][mt*16+lr][32+lq*8];
        const bf8 a2 = *(const bf8*)&gsT[w][mt*16+lr][64+lq*8];
        for (int nt = 0; nt < 2; ++nt) {
            f4 acc = {0.f,0.f,0.f,0.f};
            const bf8 b0 = *(const bf8*)&ab[nt*16+lr][lq*8];
            const bf8 b1 = *(const bf8*)&ab[nt*16+lr][32+lq*8];
            const bf8 b2 = *(const bf8*)&ab[nt*16+lr][64+lq*8];
            acc = MFMA(a0,b0,acc); acc = MFMA(a1,b1,acc); acc = MFMA(a2,b2,acc);
            const int v = nt*16+lr, o0 = mt*16+lq*4;
            const s4 xr = *(const s4*)&xs[w][v][o0];
            const float r0 = lrelu(acc.x*sc1s[o0  ]+sh1s[o0  ]+b2f(xr.x));
            const float r1 = lrelu(acc.y*sc1s[o0+1]+sh1s[o0+1]+b2f(xr.y));
            const float r2 = lrelu(acc.z*sc1s[o0+2]+sh1s[o0+2]+b2f(xr.z));
            const float r3 = lrelu(acc.w*sc1s[o0+3]+sh1s[o0+3]+b2f(xr.w));
            *(s4*)&y1[w][v][o0] = packf4(r0,r1,r2,r3);
        }
    }
    for (int mt = 0; mt < 4; ++mt) {
        const bf8 a0 = *(const bf8*)&wlf[mt*16+lr][lq*8];
        const bf8 a1 = *(const bf8*)&wlf[mt*16+lr][32+lq*8];
        for (int nt = 0; nt < 2; ++nt) {
            f4 acc = {0.f,0.f,0.f,0.f};
            const bf8 b0 = *(const bf8*)&y1[w][nt*16+lr][lq*8];
            const bf8 b1 = *(const bf8*)&y1[w][nt*16+lr][32+lq*8];
            acc = MFMA(a0,b0,acc); acc = MFMA(a1,b1,acc);
            const int v = nt*16+lr, o0 = mt*16+lq*4;
            if (v < 25) {
                const s4 xr = *(const s4*)&xs[w][v][o0];
                const float r0 = lrelu(acc.x*sc2s[o0  ]+sh2s[o0  ]+b2f(xr.x));
                const float r1 = lrelu(acc.y*sc2s[o0+1]+sh2s[o0+1]+b2f(xr.y));
                const float r2 = lrelu(acc.z*sc2s[o0+2]+sh2s[o0+2]+b2f(xr.z));
                const float r3 = lrelu(acc.w*sc2s[o0+3]+sh2s[o0+3]+b2f(xr.w));
                *(s4*)&Y[((size_t)n*3200 + t*25 + v)*64 + o0] = packf4(r0,r1,r2,r3);
            }
        }
    }
}

// temporal q/k proj -> QKT bf16 [n][t][128oc][25v]
__global__ __launch_bounds__(256) void k_qkt(
    const short* __restrict__ Y, const short* __restrict__ wb,
    const float* __restrict__ b_in_t, short* __restrict__ qkt)
{
    const int n = blockIdx.x >> 5, tc = blockIdx.x & 31, t0 = tc*4;
    const int tid = threadIdx.x;
    const int w = tid>>6, lane = tid&63, lr = lane&15, lq = lane>>4;
    __shared__ short ys[4][32][72];
    __shared__ short wi[128][72];
    for (int i = tid; i < 4*32*8; i += 256) {
        const int row = i>>3, seg = i&7, tl = row>>5, v = row&31;
        bf8 val = {0,0,0,0,0,0,0,0};
        if (v < 25) val = *(const bf8*)&Y[((size_t)n*3200 + (t0+tl)*25 + v)*64 + seg*8];
        *(bf8*)&ys[tl][v][seg*8] = val;
    }
    for (int i = tid; i < 128*8; i += 256) {
        const int o = i>>3, seg = i&7;
        *(bf8*)&wi[o][seg*8] = *(const bf8*)&wb[22528 + o*64 + seg*8];
    }
    __syncthreads();
    for (int mi = 0; mi < 2; ++mi) {
        const int mt = w*2+mi, tl = mt>>1, vh = mt&1;
        const bf8 a0 = *(const bf8*)&ys[tl][vh*16+lr][lq*8];
        const bf8 a1 = *(const bf8*)&ys[tl][vh*16+lr][32+lq*8];
        for (int nt = 0; nt < 8; ++nt) {
            f4 acc = {0.f,0.f,0.f,0.f};
            const bf8 b0 = *(const bf8*)&wi[nt*16+lr][lq*8];
            const bf8 b1 = *(const bf8*)&wi[nt*16+lr][32+lq*8];
            acc = MFMA(a0,b0,acc); acc = MFMA(a1,b1,acc);
            const int oc = nt*16+lr, v0 = vh*16+lq*4, t = t0+tl;
            const float bias = b_in_t[oc];
            const size_t base = (size_t)n*409600 + (size_t)t*3200 + oc*25 + v0;
            if (v0 < 24)
                *(s4*)&qkt[base] = packf4(acc.x+bias, acc.y+bias, acc.z+bias, acc.w+bias);
            else if (v0 == 24)
                qkt[base] = f2bs(acc.x+bias);
        }
    }
}

// temporal scores -> aT bf16 [n][ds][q][t] (zeros in masked region)
__global__ __launch_bounds__(256) void k_score_t(
    const short* __restrict__ qkt, const float* __restrict__ alphat_f,
    const float* __restrict__ alphat_b, short* __restrict__ aT)
{
    const int n = blockIdx.x >> 2, ds = blockIdx.x & 3, dir = ds>>1, s = ds&1;
    const int qoff = dir*32 + s*16, koff = 64 + dir*32 + s*16;
    const float alpha = dir ? alphat_b[s] : alphat_f[s];
    const int tid = threadIdx.x, w = tid>>6, lane = tid&63, lr = lane&15, lq = lane>>4;
    const short* qb = qkt + (size_t)n*409600;
    short* ao = aT + (size_t)(n*4+ds)*16384;
    const bf8 zf = {0,0,0,0,0,0,0,0};
    for (int ni = 0; ni < 2; ++ni) {
        const int nt = w*2+ni;
        for (int mt = 0; mt < 8; ++mt) {
            const int q = nt*16+lr, t0r = mt*16+lq*4;
            const bool skip = (dir==0) ? (mt < nt) : (mt > nt);
            if (skip) { s4 z = {0,0,0,0}; *(s4*)&ao[q*128 + t0r] = z; continue; }
            f4 acc = {0.f,0.f,0.f,0.f};
            for (int ks = 0; ks < 13; ++ks) {
                bf8 af, bf;
                if (ks==12 && lq>=2) { af = zf; bf = zf; }
                else {
                    af = *(const bf8*)&qb[(size_t)(mt*16+lr)*3200 + qoff*25 + ks*32 + lq*8];
                    bf = *(const bf8*)&qb[(size_t)(nt*16+lr)*3200 + koff*25 + ks*32 + lq*8];
                }
                acc = MFMA(af, bf, acc);
            }
            float r[4];
            #pragma unroll
            for (int j = 0; j < 4; ++j) {
                const int tt = t0r + j;
                const bool ok = (dir==0) ? (tt >= q) : (tt <= q);
                const float a = (j==0)?acc.x:((j==1)?acc.y:((j==2)?acc.z:acc.w));
                r[j] = ok ? tanhf(a*(1.f/400.f))*alpha : 0.f;
            }
            *(s4*)&ao[q*128 + t0r] = packf4(r[0],r[1],r[2],r[3]);
        }
    }
}

// ---------------------------------------------------------------------------
// Fused temporal aggregation v2. block = (n, v), 4 waves.
// Mapping: U[q][o] = sum_t aT[q][t] * PT[o][t].
//  - PT phase: wave w computes pt rows o = w*16..+15 (wave-private write).
//    B-operand (w_out_t rows) lives in regs (global-loaded, L2-hit).
//  - U phase:  m = q (A = aT rows, DIRECT from global to regs, per-wave
//    32-q slice), n = o (B = pt rows from LDS). acc[2][4] f4 across all ds.
//  - pt double-buffered -> exactly ONE barrier per ds (pt-write -> U-read);
//    barrier also drains the aT loads issued before PT (T14 overlap).
//  - triangular skip gates both aT loads and MFMAs (uniform per wave).
// LDS: ys 18.4 KB + pt[2] 34.8 KB = 53.2 KB -> 3 blocks/CU; VGPR capped via
// __launch_bounds__(256,3). Barriers 12 -> 5. ats LDS traffic eliminated.
// ---------------------------------------------------------------------------
__global__ __launch_bounds__(256, 3) void k_tagg(
    const short* __restrict__ Y, const short* __restrict__ wb,
    const short* __restrict__ aT, short* __restrict__ U)
{
    const int n = blockIdx.x / 25, v = blockIdx.x % 25;
    const int tid = threadIdx.x, w = tid>>6, lane = tid&63, lr = lane&15, lq = lane>>4;
    __shared__ short ys[128][72];       // Y[t][c] for this v        18.4 KB
    __shared__ short pt[2][64][136];    // PTl [o][t], double-buffer 34.8 KB

    for (int i = tid; i < 128*8; i += 256) {
        const int t = i>>3, seg = i&7;
        *(bf8*)&ys[t][seg*8] = *(const bf8*)&Y[((size_t)n*3200 + t*25 + v)*64 + seg*8];
    }
    // w_out_t rows for this wave's o (= w*16+lr), all 4 ds slices -> regs
    bf8 wr[4][2];
    #pragma unroll
    for (int ds = 0; ds < 4; ++ds) {
        wr[ds][0] = *(const bf8*)&wb[30720 + (w*16+lr)*256 + ds*64 + lq*8];
        wr[ds][1] = *(const bf8*)&wb[30720 + (w*16+lr)*256 + ds*64 + 32 + lq*8];
    }

    f4 acc[2][4];   // [mi][nt]: q = (2w+mi)*16+lq*4+j, o = nt*16+lr
    #pragma unroll
    for (int mi = 0; mi < 2; ++mi)
        #pragma unroll
        for (int nt = 0; nt < 4; ++nt) { acc[mi][nt].x=0.f; acc[mi][nt].y=0.f; acc[mi][nt].z=0.f; acc[mi][nt].w=0.f; }

    __syncthreads();   // ys ready

    #pragma unroll
    for (int ds = 0; ds < 4; ++ds) {
        const int dir = ds>>1, buf = ds&1;
        // A-frags (aT rows q for this wave) -> regs; in flight during PT
        bf8 ar[2][4];
        #pragma unroll
        for (int mi = 0; mi < 2; ++mi) {
            const int qt = 2*w + mi;
            #pragma unroll
            for (int ks = 0; ks < 4; ++ks) {
                const bool skip = (dir==0) ? (ks*32+31 < qt*16) : (ks*32 > qt*16+15);
                if (!skip)
                    ar[mi][ks] = *(const bf8*)&aT[(size_t)(n*4+ds)*16384
                                                  + (qt*16+lr)*128 + ks*32 + lq*8];
            }
        }
        // PT: rows o = w*16+lr (wave-private; no barrier needed for pt write)
        {
            const bf8 b0 = wr[ds][0], b1 = wr[ds][1];
            #pragma unroll
            for (int tt = 0; tt < 8; ++tt) {
                f4 p = {0.f,0.f,0.f,0.f};
                const bf8 a0 = *(const bf8*)&ys[tt*16+lr][lq*8];
                const bf8 a1 = *(const bf8*)&ys[tt*16+lr][32+lq*8];
                p = MFMA(a0,b0,p); p = MFMA(a1,b1,p);
                *(s4*)&pt[buf][w*16+lr][tt*16+lq*4] = packf4(p.x,p.y,p.z,p.w);
            }
        }
        __syncthreads();   // pt[buf] visible to all waves; ar loads drained
        // U accumulate: A = ar (q rows), B = pt[buf] (o rows)
        #pragma unroll
        for (int ks = 0; ks < 4; ++ks) {
            const bool skip0 = (dir==0) ? (ks*32+31 < (2*w)*16)   : (ks*32 > (2*w)*16+15);
            const bool skip1 = (dir==0) ? (ks*32+31 < (2*w+1)*16) : (ks*32 > (2*w+1)*16+15);
            if (skip0 && skip1) continue;
            bf8 bfr[4];
            #pragma unroll
            for (int nt = 0; nt < 4; ++nt)
                bfr[nt] = *(const bf8*)&pt[buf][nt*16+lr][ks*32+lq*8];
            if (!skip0) {
                #pragma unroll
                for (int nt = 0; nt < 4; ++nt)
                    acc[0][nt] = MFMA(ar[0][ks], bfr[nt], acc[0][nt]);
            }
            if (!skip1) {
                #pragma unroll
                for (int nt = 0; nt < 4; ++nt)
                    acc[1][nt] = MFMA(ar[1][ks], bfr[nt], acc[1][nt]);
            }
        }
        // no second barrier: next ds writes pt[buf^1]; pt[buf] reads are done
        // by every wave before the NEXT barrier, which precedes any overwrite.
    }
    // write U[q][v][o]: lane holds q = (2w+mi)*16+lq*4+j, o = nt*16+lr
    #pragma unroll
    for (int mi = 0; mi < 2; ++mi) {
        #pragma unroll
        for (int j = 0; j < 4; ++j) {
            const int q = (2*w+mi)*16 + lq*4 + j;
            short* ub = &U[((size_t)(n*128+q)*25 + v)*64 + lr];
            ub[0]  = f2bs(acc[mi][0][j]);
            ub[16] = f2bs(acc[mi][1][j]);
            ub[32] = f2bs(acc[mi][2][j]);
            ub[48] = f2bs(acc[mi][3][j]);
        }
    }
}

// temporal ff block: z1 = lrelu(y + u*sc1+sh1); Y = lrelu(y + BN(Wff@z1)) in-place
__global__ __launch_bounds__(256) void k_temporal(
    const short* __restrict__ U, short* __restrict__ Y, const short* __restrict__ wb,
    const float* __restrict__ b_out, const float* __restrict__ bn_out,
    const float* __restrict__ b_ff,  const float* __restrict__ bn_ff)
{
    const int n = blockIdx.x >> 5, qc = blockIdx.x & 31, q0 = qc*4;
    const int tid = threadIdx.x, w = tid>>6, lane = tid&63, lr = lane&15, lq = lane>>4;
    __shared__ short zs[112][72];
    __shared__ short z1[112][72];
    __shared__ short zout[112][72];
    __shared__ short wf[64][72];
    __shared__ float sc1s[64], sh1s[64], sc2s[64], sh2s[64];
    if (tid < 64) {
        float g=bn_out[tid], bb=bn_out[64+tid], m=bn_out[128+tid], vv=bn_out[192+tid];
        float inv = g*rsqrtf(vv+BN_EPS);
        sc1s[tid]=inv; sh1s[tid]=(b_out[tid]-m)*inv+bb;
        g=bn_ff[tid]; bb=bn_ff[64+tid]; m=bn_ff[128+tid]; vv=bn_ff[192+tid];
        inv = g*rsqrtf(vv+BN_EPS);
        sc2s[tid]=inv; sh2s[tid]=(b_ff[tid]-m)*inv+bb;
    }
    for (int i = tid; i < 64*8; i += 256) {
        const int o = i>>3, seg = i&7;
        *(bf8*)&wf[o][seg*8] = *(const bf8*)&wb[47104 + o*64 + seg*8];
    }
    __syncthreads();
    for (int i = tid; i < 112*8; i += 256) {
        const int row = i>>3, seg = i&7;
        bf8 yv = {0,0,0,0,0,0,0,0}, zv = yv;
        if (row < 100) {
            const int q = q0 + row/25, v = row%25;
            yv = *(const bf8*)&Y[((size_t)n*3200 + q*25 + v)*64 + seg*8];
            const bf8 uv = *(const bf8*)&U[((size_t)(n*128+q)*25 + v)*64 + seg*8];
            #pragma unroll
            for (int j = 0; j < 8; ++j) {
                const int o = seg*8+j;
                zv[j] = f2bs(lrelu(b2f(yv[j]) + b2f(uv[j])*sc1s[o] + sh1s[o]));
            }
        }
        *(bf8*)&zs[row][seg*8] = yv;
        *(bf8*)&z1[row][seg*8] = zv;
    }
    __syncthreads();
    const bf8 a0 = *(const bf8*)&wf[w*16+lr][lq*8];
    const bf8 a1 = *(const bf8*)&wf[w*16+lr][32+lq*8];
    for (int nt = 0; nt < 7; ++nt) {
        f4 acc = {0.f,0.f,0.f,0.f};
        const bf8 b0 = *(const bf8*)&z1[nt*16+lr][lq*8];
        const bf8 b1 = *(const bf8*)&z1[nt*16+lr][32+lq*8];
        acc = MFMA(a0,b0,acc); acc = MFMA(a1,b1,acc);
        const int px = nt*16+lr, o0 = w*16+lq*4;
        const s4 yr = *(const s4*)&zs[px][o0];
        const float r0 = lrelu(acc.x*sc2s[o0  ]+sh2s[o0  ]+b2f(yr.x));
        const float r1 = lrelu(acc.y*sc2s[o0+1]+sh2s[o0+1]+b2f(yr.y));
        const float r2 = lrelu(acc.z*sc2s[o0+2]+sh2s[o0+2]+b2f(yr.z));
        const float r3 = lrelu(acc.w*sc2s[o0+3]+sh2s[o0+3]+b2f(yr.w));
        *(s4*)&zout[px][o0] = packf4(r0,r1,r2,r3);
    }
    __syncthreads();
    for (int i = tid; i < 100*8; i += 256) {
        const int row = i>>3, seg = i&7;
        *(bf8*)&Y[((size_t)n*3200 + q0*25 + row)*64 + seg*8] = *(const bf8*)&zout[row][seg*8];
    }
}

// ---------------------------------------------------------------------------
// tcn v3: weights in regs; bfr hoisted per nn; 8 interleaved accumulators;
// direct global stores from MFMA D-layout (no yout LDS round-trip).
// ---------------------------------------------------------------------------
__global__ __launch_bounds__(256, 2) void k_tcn(
    const short* __restrict__ Y, const short* __restrict__ wb,
    const float* __restrict__ b, const float* __restrict__ bn,
    float* __restrict__ out)
{
    const int n = blockIdx.x >> 5, tc = (blockIdx.x >> 1) & 15, oh = blockIdx.x & 1;
    const int t0 = tc*8;
    const int tid = threadIdx.x, w = tid>>6, lane = tid&63, lr = lane&15, lq = lane>>4;
    __shared__ short zs[352][72];
    __shared__ float scs[32], shs[32];

    // weights -> registers (issued first; overlap LDS staging below)
    bf8 af[2][14];
    #pragma unroll
    for (int mt = 0; mt < 2; ++mt)
        #pragma unroll
        for (int st = 0; st < 14; ++st)
            af[mt][st] = *(const bf8*)&wb[51200 + (oh*32 + mt*16 + lr)*448 + st*32 + lq*8];

    if (tid < 32) {
        const int o = oh*32 + tid;
        const float g=bn[o], bb=bn[64+o], m=bn[128+o], vv=bn[192+o];
        const float inv = g*rsqrtf(vv+BN_EPS);
        scs[tid]=inv; shs[tid]=(b[o]-m)*inv+bb;
    }
    for (int i = tid; i < 352*8; i += 256) {
        const int row = i>>3, seg = i&7;
        bf8 val = {0,0,0,0,0,0,0,0};
        if (row < 350) {
            const int tlp = row/25, v = row%25, t = t0 - 3 + tlp;
            if (t >= 0 && t < 128)
                val = *(const bf8*)&Y[((size_t)n*3200 + t*25 + v)*64 + seg*8];
        }
        *(bf8*)&zs[row][seg*8] = val;
    }
    __syncthreads();
    for (int nn = 0; nn < 4; ++nn) {
        const int nt = w + nn*4;
        if (nt >= 13) break;
        // pixel fragments for this nt, shared by both mt
        bf8 bfr[14];
        #pragma unroll
        for (int st = 0; st < 14; ++st)
            bfr[st] = *(const bf8*)&zs[nt*16 + lr + (st>>1)*25][(st&1)*32 + lq*8];
        // 28 MFMA, 8 accumulators interleaved
        f4 ac[2][4];
        #pragma unroll
        for (int m2 = 0; m2 < 2; ++m2)
            #pragma unroll
            for (int j = 0; j < 4; ++j) { ac[m2][j].x=0.f; ac[m2][j].y=0.f; ac[m2][j].z=0.f; ac[m2][j].w=0.f; }
        #pragma unroll
        for (int st = 0; st < 14; ++st) {
            ac[0][st&3] = MFMA(af[0][st], bfr[st], ac[0][st&3]);
            ac[1][st&3] = MFMA(af[1][st], bfr[st], ac[1][st&3]);
        }
        const int px = nt*16+lr;
        if (px < 200) {
            #pragma unroll
            for (int mt = 0; mt < 2; ++mt) {
                const float ax = ac[mt][0].x+ac[mt][1].x+ac[mt][2].x+ac[mt][3].x;
                const float ay = ac[mt][0].y+ac[mt][1].y+ac[mt][2].y+ac[mt][3].y;
                const float az = ac[mt][0].z+ac[mt][1].z+ac[mt][2].z+ac[mt][3].z;
                const float aw = ac[mt][0].w+ac[mt][1].w+ac[mt][2].w+ac[mt][3].w;
                const int o0l = mt*16+lq*4;
                const s4 zr = *(const s4*)&zs[px+75][oh*32+o0l];
                float* ob = out + (size_t)n*204800 + (size_t)(oh*32+o0l)*3200 + t0*25 + px;
                ob[0]    = lrelu(ax*scs[o0l  ]+shs[o0l  ]+b2f(zr.x));
                ob[3200] = lrelu(ay*scs[o0l+1]+shs[o0l+1]+b2f(zr.y));
                ob[6400] = lrelu(az*scs[o0l+2]+shs[o0l+2]+b2f(zr.z));
                ob[9600] = lrelu(aw*scs[o0l+3]+shs[o0l+3]+b2f(zr.w));
            }
        }
    }
}

// ---------------------------------------------------------------------------
extern "C" void kernel_launch(void* const* d_in, const int* in_sizes, int n_in,
                              void* d_out, int out_size, void* d_ws, size_t ws_size,
                              hipStream_t stream) {
    const float* x        = (const float*)d_in[0];
    const float* w_in_s   = (const float*)d_in[1];
    const float* b_in_s   = (const float*)d_in[2];
    const float* alphas   = (const float*)d_in[3];
    const float* att0s    = (const float*)d_in[4];
    const float* w_out_s  = (const float*)d_in[5];
    const float* b_out_s  = (const float*)d_in[6];
    const float* bn_out_s = (const float*)d_in[7];
    const float* w_ff_s   = (const float*)d_in[8];
    const float* b_ff_s   = (const float*)d_in[9];
    const float* bn_ff_s  = (const float*)d_in[10];
    const float* w_in_t   = (const float*)d_in[11];
    const float* b_in_t   = (const float*)d_in[12];
    const float* alphat_f = (const float*)d_in[13];
    const float* alphat_b = (const float*)d_in[14];
    const float* w_out_t  = (const float*)d_in[15];
    const float* b_out_t  = (const float*)d_in[16];
    const float* bn_out_t = (const float*)d_in[17];
    const float* w_ff_t   = (const float*)d_in[18];
    const float* b_ff_t   = (const float*)d_in[19];
    const float* bn_ff_t  = (const float*)d_in[20];
    const float* w_tcn    = (const float*)d_in[21];
    const float* b_tcn    = (const float*)d_in[22];
    const float* bn_tcn   = (const float*)d_in[23];
    float* out = (float*)d_out;
    char* ws = (char*)d_ws;

    short* wb    = (short*)(ws + 0);
    short* attnB = (short*)(ws + 4102144);
    short* Y     = (short*)(ws + 4888576);
    short* aT    = (short*)(ws + 57317376);
    short* XB    = (short*)(ws + 74094592);           // phase 1
    short* QKT   = (short*)(ws + 74094592);           // phase 2 (XB dead)
    short* U     = (short*)(ws + 74094592 + 52428800);

    k_prep<<<64, 256, 0, stream>>>(w_in_s, w_out_s, w_ff_s, w_in_t, w_out_t, w_ff_t, w_tcn, wb);
    k_x2b<<<2048, 256, 0, stream>>>(x, XB);
    k_attn_s<<<NN * 3, 256, 0, stream>>>(XB, wb, b_in_s, alphas, att0s, attnB);
    k_spatial<<<4096, 256, 0, stream>>>(XB, attnB, wb, b_out_s, bn_out_s, b_ff_s, bn_ff_s, Y);
    k_qkt<<<4096, 256, 0, stream>>>(Y, wb, b_in_t, QKT);
    k_score_t<<<512, 256, 0, stream>>>(QKT, alphat_f, alphat_b, aT);
    k_tagg<<<NN * 25, 256, 0, stream>>>(Y, wb, aT, U);
    k_temporal<<<4096, 256, 0, stream>>>(U, Y, wb, b_out_t, bn_out_t, b_ff_t, bn_ff_t);
    k_tcn<<<4096, 256, 0, stream>>>(Y, wb, b_tcn, bn_tcn, out);
}

// Round 5
// 691.000 us; speedup vs baseline: 1.2051x; 1.0343x over previous
//
#include <hip/hip_runtime.h>
#include <math.h>

#define NN   128
#define TTc  128
#define VVc  25
#define TV   3200
#define BN_EPS 1e-5f

typedef __attribute__((ext_vector_type(8))) short bf8;   // 8 bf16 in 4 VGPRs
typedef __attribute__((ext_vector_type(4))) short s4;    // 4 bf16 (b64)
typedef __attribute__((ext_vector_type(4))) float f4;    // MFMA accumulator

#define MFMA(a,b,c) __builtin_amdgcn_mfma_f32_16x16x32_bf16(a,b,c,0,0,0)

__device__ __forceinline__ float lrelu(float a){ return a>=0.f ? a : 0.1f*a; }
__device__ __forceinline__ short f2bs(float f){
    union{float f; unsigned u;} x; x.f = f;
    unsigned r = x.u + 0x7FFF + ((x.u>>16)&1);
    return (short)(r>>16);
}
__device__ __forceinline__ float b2f(short s){
    union{unsigned u; float f;} x; x.u = ((unsigned)(unsigned short)s)<<16; return x.f;
}
__device__ __forceinline__ s4 packf4(float a,float b,float c,float d){
    s4 r; r.x=f2bs(a); r.y=f2bs(b); r.z=f2bs(c); r.w=f2bs(d); return r;
}

// ---------------------------------------------------------------------------
// Workspace layout (total 178,952,192 B, proven OK):
//  wb bf16 weights       : byte 0
//  attnB bf16 [n][32v][96]: byte 4102144
//  Y  bf16 [n][3200][64] : byte 4888576
//  aT bf16 [n][4][q][t]  : byte 57317376
//  R  : byte 74094592 : XB -> QKT
//  U  : byte 74094592+52428800
// wb element offsets: w_in_s 0 [96][64]; w_out_s 6144 [64][192]; w_ff_s 18432
//  [64][64]; w_in_t 22528 [128][64]; w_out_t 30720 [64][256]; w_ff_t 47104
//  [64][64]; wt 51200 [64][448] (o, dt*64+c)
// ---------------------------------------------------------------------------

__global__ __launch_bounds__(256) void k_prep(
    const float* __restrict__ w_in_s, const float* __restrict__ w_out_s,
    const float* __restrict__ w_ff_s, const float* __restrict__ w_in_t,
    const float* __restrict__ w_out_t, const float* __restrict__ w_ff_t,
    const float* __restrict__ w_tcn, short* __restrict__ wb)
{
    const int total = 51200 + 64*448;
    for (int i = blockIdx.x*256 + threadIdx.x; i < total; i += gridDim.x*256) {
        float v;
        if      (i < 6144)  v = w_in_s[i];
        else if (i < 18432) v = w_out_s[i-6144];
        else if (i < 22528) v = w_ff_s[i-18432];
        else if (i < 30720) v = w_in_t[i-22528];
        else if (i < 47104) v = w_out_t[i-30720];
        else if (i < 51200) v = w_ff_t[i-47104];
        else { int j=i-51200; int o=j/448; int r=j%448; int dt=r>>6; int c=r&63;
               v = w_tcn[(o*64+c)*7 + dt]; }
        wb[i] = f2bs(v);
    }
}

// x f32 [n][c][t][v] -> XB bf16 pixel-major [n][t*25+v][64]
// [203] pad: lane stride 4 rows = 812 dw == 12 mod 32 -> 2-way (free).
__global__ __launch_bounds__(256) void k_x2b(const float* __restrict__ x, short* __restrict__ XB)
{
    const int n = blockIdx.x >> 4, tc = blockIdx.x & 15, t0 = tc*8;
    const int tid = threadIdx.x;
    __shared__ float xs[64][203];
    const float* xb = x + (size_t)n*204800 + t0*25;
    for (int i = tid; i < 64*200; i += 256) { int c=i/200, p=i%200; xs[c][p] = xb[(size_t)c*3200 + p]; }
    __syncthreads();
    short* ob = XB + (size_t)n*204800 + t0*25*64;
    for (int i = tid; i < 200*16; i += 256) {
        const int p = i>>4, c0 = (i&15)<<2;
        *(s4*)&ob[p*64 + c0] = packf4(xs[c0][p], xs[c0+1][p], xs[c0+2][p], xs[c0+3][p]);
    }
}

// ---------------------------------------------------------------------------
// Fused spatial attention scores (MFMA). grid = N*SS, 4 waves.
// ---------------------------------------------------------------------------
__global__ __launch_bounds__(256) void k_attn_s(
    const short* __restrict__ XB, const short* __restrict__ wb,
    const float* __restrict__ b_in_s, const float* __restrict__ alphas,
    const float* __restrict__ att0s, short* __restrict__ attnB)
{
    const int n = blockIdx.x / 3, s = blockIdx.x % 3;
    const int tid = threadIdx.x, w = tid>>6, lane = tid&63, lr = lane&15, lq = lane>>4;
    __shared__ short ys[208][72];     // staged pixels [px][64c]
    __shared__ short qkl[208][40];    // projected [px][32ch]: 0-15 q, 16-31 k
    __shared__ short wsl[32][72];     // weight rows (q 16 + k 16) x 64c
    __shared__ float bl[32];

    for (int i = tid; i < 32*8; i += 256) {
        const int cl = i>>3, seg = i&7;
        const int row = (cl < 16) ? (s*16 + cl) : (48 + s*16 + (cl-16));
        *(bf8*)&wsl[cl][seg*8] = *(const bf8*)&wb[row*64 + seg*8];
    }
    if (tid < 32) {
        const int row = (tid < 16) ? (s*16 + tid) : (48 + s*16 + (tid-16));
        bl[tid] = b_in_s[row];
    }

    const int mt = w>>1, sn = w&1;     // this wave's score tile (u-tile, v-tile)
    f4 acc = {0.f,0.f,0.f,0.f};

    for (int ch = 0; ch < 16; ++ch) {
        __syncthreads();   // qkl/ys from prev iter fully consumed
        for (int i = tid; i < 208*8; i += 256) {
            const int row = i>>3, seg = i&7;
            bf8 val = {0,0,0,0,0,0,0,0};
            if (row < 200)
                val = *(const bf8*)&XB[((size_t)n*3200 + ch*200 + row)*64 + seg*8];
            *(bf8*)&ys[row][seg*8] = val;
        }
        __syncthreads();
        // projection: wave w covers px-tiles {w, w+4, w+8, w+12}
        for (int nn = 0; nn < 4; ++nn) {
            const int nt2 = w + nn*4;
            if (nt2 >= 13) break;
            const bf8 b0 = *(const bf8*)&ys[nt2*16+lr][lq*8];
            const bf8 b1 = *(const bf8*)&ys[nt2*16+lr][32+lq*8];
            for (int mt2 = 0; mt2 < 2; ++mt2) {
                f4 pa = {0.f,0.f,0.f,0.f};
                const bf8 a0 = *(const bf8*)&wsl[mt2*16+lr][lq*8];
                const bf8 a1 = *(const bf8*)&wsl[mt2*16+lr][32+lq*8];
                pa = MFMA(a0,b0,pa); pa = MFMA(a1,b1,pa);
                const int px = nt2*16+lr, c0 = mt2*16+lq*4;
                *(s4*)&qkl[px][c0] =
                    packf4(pa.x+bl[c0], pa.y+bl[c0+1], pa.z+bl[c0+2], pa.w+bl[c0+3]);
            }
        }
        __syncthreads();
        // score accumulate: k = (t_local, c), 4 steps of 32
        for (int ks = 0; ks < 4; ++ks) {
            const int tl = ks*2 + (lq>>1);
            const bf8 af = *(const bf8*)&qkl[tl*25 + mt*16+lr][(lq&1)*8];
            const bf8 bf = *(const bf8*)&qkl[tl*25 + sn*16+lr][16 + (lq&1)*8];
            acc = MFMA(af, bf, acc);
        }
    }
    const float alpha = alphas[s];
    const int v = sn*16 + lr, u0 = mt*16 + lq*4;
    float r[4];
    #pragma unroll
    for (int j = 0; j < 4; ++j) {
        const int u = u0 + j;
        const float a = (j==0)?acc.x:((j==1)?acc.y:((j==2)?acc.z:acc.w));
        r[j] = (u < 25 && v < 25)
             ? tanhf(a*(1.f/2048.f))*alpha + att0s[s*625 + u*25 + v] : 0.f;
    }
    *(s4*)&attnB[(size_t)n*3072 + v*96 + s*32 + u0] = packf4(r[0],r[1],r[2],r[3]);
}

// ---------------------------------------------------------------------------
// fused spatial block v2 (MFMA). block=(n, t-chunk4), wave w owns t=t0+w.
//  - s outer loop: gst holds ONE s-slice [o][u] (wave-private, no barriers);
//    phase-2 accumulates into persistent acc2[4][2] regs (same s0,s1,s2 order).
//  - wlo/wlf/ab operand fragments live in REGISTERS (direct global loads,
//    L2-resident) -> three LDS staging loops deleted.
// LDS: xs 18.4 + gst 20.5 + y1 18.4 + scales 1 = 58.3 KB -> 2 blocks/CU.
// ---------------------------------------------------------------------------
__global__ __launch_bounds__(256, 2) void k_spatial(
    const short* __restrict__ XB, const short* __restrict__ attnB, const short* __restrict__ wb,
    const float* __restrict__ b_out, const float* __restrict__ bn_out,
    const float* __restrict__ b_ff,  const float* __restrict__ bn_ff,
    short* __restrict__ Y)
{
    const int n = blockIdx.x >> 5, tc = blockIdx.x & 31, t0 = tc*4;
    const int tid = threadIdx.x;
    const int w = tid>>6, lane = tid&63, lr = lane&15, lq = lane>>4;
    __shared__ short xs[4][32][72];     // pixels [t][v][c]          18.4 KB
    __shared__ short gst[4][64][40];    // per-s gs [o][u]           20.5 KB
    __shared__ short y1[4][32][72];     // intermediate [v][c]       18.4 KB
    __shared__ float sc1s[64], sh1s[64], sc2s[64], sh2s[64];   //     1.0 KB

    // --- operand fragments -> registers (L2-resident, issued first) ---
    // ab: phase-2 B rows v = nt*16+lr, k-slice u = s*32+lq*8
    bf8 abf[2][3];
    #pragma unroll
    for (int nt = 0; nt < 2; ++nt)
        #pragma unroll
        for (int s = 0; s < 3; ++s)
            abf[nt][s] = *(const bf8*)&attnB[(size_t)n*3072 + (nt*16+lr)*96 + s*32 + lq*8];
    // wlf: phase-3 A rows o = mt*16+lr, k = c
    bf8 wff[4][2];
    #pragma unroll
    for (int mt = 0; mt < 4; ++mt) {
        wff[mt][0] = *(const bf8*)&wb[18432 + (mt*16+lr)*64 + lq*8];
        wff[mt][1] = *(const bf8*)&wb[18432 + (mt*16+lr)*64 + 32 + lq*8];
    }

    for (int i = tid; i < 4*32*8; i += 256) {
        const int row = i>>3, seg = i&7, tl = row>>5, uv = row&31;
        bf8 val = {0,0,0,0,0,0,0,0};
        if (uv < 25) val = *(const bf8*)&XB[((size_t)n*3200 + (t0+tl)*25 + uv)*64 + seg*8];
        *(bf8*)&xs[tl][uv][seg*8] = val;
    }
    if (tid < 64) {
        float g=bn_out[tid], bb=bn_out[64+tid], m=bn_out[128+tid], vv=bn_out[192+tid];
        float inv = g*rsqrtf(vv+BN_EPS);
        sc1s[tid]=inv; sh1s[tid]=(b_out[tid]-m)*inv+bb;
        g=bn_ff[tid]; bb=bn_ff[64+tid]; m=bn_ff[128+tid]; vv=bn_ff[192+tid];
        inv = g*rsqrtf(vv+BN_EPS);
        sc2s[tid]=inv; sh2s[tid]=(b_ff[tid]-m)*inv+bb;
    }
    __syncthreads();   // xs + scales ready (only barrier in the kernel)

    f4 acc2[4][2];   // [mt(o-tile)][nt(v-tile)]: row o = mt*16+lq*4+j, col v = nt*16+lr
    #pragma unroll
    for (int mt = 0; mt < 4; ++mt)
        #pragma unroll
        for (int nt = 0; nt < 2; ++nt) { acc2[mt][nt].x=0.f; acc2[mt][nt].y=0.f; acc2[mt][nt].z=0.f; acc2[mt][nt].w=0.f; }

    #pragma unroll
    for (int s = 0; s < 3; ++s) {
        // wlo: phase-1 B rows o = nt*16+lr, k-slice c = s*64+{0,32}+lq*8
        bf8 wof[4][2];
        #pragma unroll
        for (int nt = 0; nt < 4; ++nt) {
            wof[nt][0] = *(const bf8*)&wb[6144 + (nt*16+lr)*192 + s*64 + lq*8];
            wof[nt][1] = *(const bf8*)&wb[6144 + (nt*16+lr)*192 + s*64 + 32 + lq*8];
        }
        // phase 1: gs_s[u][o] = x[u][c] @ w_out_s[o][s*64+c] -> gst[w][o][u]
        #pragma unroll
        for (int mt = 0; mt < 2; ++mt) {
            const bf8 a0 = *(const bf8*)&xs[w][mt*16+lr][lq*8];
            const bf8 a1 = *(const bf8*)&xs[w][mt*16+lr][32+lq*8];
            #pragma unroll
            for (int nt = 0; nt < 4; ++nt) {
                f4 acc = {0.f,0.f,0.f,0.f};
                acc = MFMA(a0, wof[nt][0], acc);
                acc = MFMA(a1, wof[nt][1], acc);
                // lane: rows u = mt*16+lq*4+j, col o = nt*16+lr
                *(s4*)&gst[w][nt*16+lr][mt*16+lq*4] = packf4(acc.x,acc.y,acc.z,acc.w);
            }
        }
        // phase 2: acc2[o][v] += gs_s[o][u] @ ab_s[v][u]   (wave-private gst)
        #pragma unroll
        for (int mt = 0; mt < 4; ++mt) {
            const bf8 a = *(const bf8*)&gst[w][mt*16+lr][lq*8];
            #pragma unroll
            for (int nt = 0; nt < 2; ++nt)
                acc2[mt][nt] = MFMA(a, abf[nt][s], acc2[mt][nt]);
        }
    }

    const int t = t0 + w;
    // epilogue 1: y1 = lrelu(x + BN(acc2))
    #pragma unroll
    for (int mt = 0; mt < 4; ++mt) {
        #pragma unroll
        for (int nt = 0; nt < 2; ++nt) {
            const int v = nt*16+lr, o0 = mt*16+lq*4;
            const f4 acc = acc2[mt][nt];
            const s4 xr = *(const s4*)&xs[w][v][o0];
            const float r0 = lrelu(acc.x*sc1s[o0  ]+sh1s[o0  ]+b2f(xr.x));
            const float r1 = lrelu(acc.y*sc1s[o0+1]+sh1s[o0+1]+b2f(xr.y));
            const float r2 = lrelu(acc.z*sc1s[o0+2]+sh1s[o0+2]+b2f(xr.z));
            const float r3 = lrelu(acc.w*sc1s[o0+3]+sh1s[o0+3]+b2f(xr.w));
            *(s4*)&y1[w][v][o0] = packf4(r0,r1,r2,r3);
        }
    }
    // phase 3: Y = lrelu(x + BN(w_ff_s @ y1))
    #pragma unroll
    for (int mt = 0; mt < 4; ++mt) {
        #pragma unroll
        for (int nt = 0; nt < 2; ++nt) {
            f4 acc = {0.f,0.f,0.f,0.f};
            const bf8 b0 = *(const bf8*)&y1[w][nt*16+lr][lq*8];
            const bf8 b1 = *(const bf8*)&y1[w][nt*16+lr][32+lq*8];
            acc = MFMA(wff[mt][0],b0,acc); acc = MFMA(wff[mt][1],b1,acc);
            const int v = nt*16+lr, o0 = mt*16+lq*4;
            if (v < 25) {
                const s4 xr = *(const s4*)&xs[w][v][o0];
                const float r0 = lrelu(acc.x*sc2s[o0  ]+sh2s[o0  ]+b2f(xr.x));
                const float r1 = lrelu(acc.y*sc2s[o0+1]+sh2s[o0+1]+b2f(xr.y));
                const float r2 = lrelu(acc.z*sc2s[o0+2]+sh2s[o0+2]+b2f(xr.z));
                const float r3 = lrelu(acc.w*sc2s[o0+3]+sh2s[o0+3]+b2f(xr.w));
                *(s4*)&Y[((size_t)n*3200 + t*25 + v)*64 + o0] = packf4(r0,r1,r2,r3);
            }
        }
    }
}

// temporal q/k proj -> QKT bf16 [n][t][128oc][25v]
__global__ __launch_bounds__(256) void k_qkt(
    const short* __restrict__ Y, const short* __restrict__ wb,
    const float* __restrict__ b_in_t, short* __restrict__ qkt)
{
    const int n = blockIdx.x >> 5, tc = blockIdx.x & 31, t0 = tc*4;
    const int tid = threadIdx.x;
    const int w = tid>>6, lane = tid&63, lr = lane&15, lq = lane>>4;
    __shared__ short ys[4][32][72];
    __shared__ short wi[128][72];
    for (int i = tid; i < 4*32*8; i += 256) {
        const int row = i>>3, seg = i&7, tl = row>>5, v = row&31;
        bf8 val = {0,0,0,0,0,0,0,0};
        if (v < 25) val = *(const bf8*)&Y[((size_t)n*3200 + (t0+tl)*25 + v)*64 + seg*8];
        *(bf8*)&ys[tl][v][seg*8] = val;
    }
    for (int i = tid; i < 128*8; i += 256) {
        const int o = i>>3, seg = i&7;
        *(bf8*)&wi[o][seg*8] = *(const bf8*)&wb[22528 + o*64 + seg*8];
    }
    __syncthreads();
    for (int mi = 0; mi < 2; ++mi) {
        const int mt = w*2+mi, tl = mt>>1, vh = mt&1;
        const bf8 a0 = *(const bf8*)&ys[tl][vh*16+lr][lq*8];
        const bf8 a1 = *(const bf8*)&ys[tl][vh*16+lr][32+lq*8];
        for (int nt = 0; nt < 8; ++nt) {
            f4 acc = {0.f,0.f,0.f,0.f};
            const bf8 b0 = *(const bf8*)&wi[nt*16+lr][lq*8];
            const bf8 b1 = *(const bf8*)&wi[nt*16+lr][32+lq*8];
            acc = MFMA(a0,b0,acc); acc = MFMA(a1,b1,acc);
            const int oc = nt*16+lr, v0 = vh*16+lq*4, t = t0+tl;
            const float bias = b_in_t[oc];
            const size_t base = (size_t)n*409600 + (size_t)t*3200 + oc*25 + v0;
            if (v0 < 24)
                *(s4*)&qkt[base] = packf4(acc.x+bias, acc.y+bias, acc.z+bias, acc.w+bias);
            else if (v0 == 24)
                qkt[base] = f2bs(acc.x+bias);
        }
    }
}

// temporal scores -> aT bf16 [n][ds][q][t] (zeros in masked region)
__global__ __launch_bounds__(256) void k_score_t(
    const short* __restrict__ qkt, const float* __restrict__ alphat_f,
    const float* __restrict__ alphat_b, short* __restrict__ aT)
{
    const int n = blockIdx.x >> 2, ds = blockIdx.x & 3, dir = ds>>1, s = ds&1;
    const int qoff = dir*32 + s*16, koff = 64 + dir*32 + s*16;
    const float alpha = dir ? alphat_b[s] : alphat_f[s];
    const int tid = threadIdx.x, w = tid>>6, lane = tid&63, lr = lane&15, lq = lane>>4;
    const short* qb = qkt + (size_t)n*409600;
    short* ao = aT + (size_t)(n*4+ds)*16384;
    const bf8 zf = {0,0,0,0,0,0,0,0};
    for (int ni = 0; ni < 2; ++ni) {
        const int nt = w*2+ni;
        for (int mt = 0; mt < 8; ++mt) {
            const int q = nt*16+lr, t0r = mt*16+lq*4;
            const bool skip = (dir==0) ? (mt < nt) : (mt > nt);
            if (skip) { s4 z = {0,0,0,0}; *(s4*)&ao[q*128 + t0r] = z; continue; }
            f4 acc = {0.f,0.f,0.f,0.f};
            for (int ks = 0; ks < 13; ++ks) {
                bf8 af, bf;
                if (ks==12 && lq>=2) { af = zf; bf = zf; }
                else {
                    af = *(const bf8*)&qb[(size_t)(mt*16+lr)*3200 + qoff*25 + ks*32 + lq*8];
                    bf = *(const bf8*)&qb[(size_t)(nt*16+lr)*3200 + koff*25 + ks*32 + lq*8];
                }
                acc = MFMA(af, bf, acc);
            }
            float r[4];
            #pragma unroll
            for (int j = 0; j < 4; ++j) {
                const int tt = t0r + j;
                const bool ok = (dir==0) ? (tt >= q) : (tt <= q);
                const float a = (j==0)?acc.x:((j==1)?acc.y:((j==2)?acc.z:acc.w));
                r[j] = ok ? tanhf(a*(1.f/400.f))*alpha : 0.f;
            }
            *(s4*)&ao[q*128 + t0r] = packf4(r[0],r[1],r[2],r[3]);
        }
    }
}

// ---------------------------------------------------------------------------
// Fused temporal aggregation v2. block = (n, v), 4 waves.
// ---------------------------------------------------------------------------
__global__ __launch_bounds__(256, 3) void k_tagg(
    const short* __restrict__ Y, const short* __restrict__ wb,
    const short* __restrict__ aT, short* __restrict__ U)
{
    const int n = blockIdx.x / 25, v = blockIdx.x % 25;
    const int tid = threadIdx.x, w = tid>>6, lane = tid&63, lr = lane&15, lq = lane>>4;
    __shared__ short ys[128][72];       // Y[t][c] for this v        18.4 KB
    __shared__ short pt[2][64][136];    // PTl [o][t], double-buffer 34.8 KB

    for (int i = tid; i < 128*8; i += 256) {
        const int t = i>>3, seg = i&7;
        *(bf8*)&ys[t][seg*8] = *(const bf8*)&Y[((size_t)n*3200 + t*25 + v)*64 + seg*8];
    }
    // w_out_t rows for this wave's o (= w*16+lr), all 4 ds slices -> regs
    bf8 wr[4][2];
    #pragma unroll
    for (int ds = 0; ds < 4; ++ds) {
        wr[ds][0] = *(const bf8*)&wb[30720 + (w*16+lr)*256 + ds*64 + lq*8];
        wr[ds][1] = *(const bf8*)&wb[30720 + (w*16+lr)*256 + ds*64 + 32 + lq*8];
    }

    f4 acc[2][4];   // [mi][nt]: q = (2w+mi)*16+lq*4+j, o = nt*16+lr
    #pragma unroll
    for (int mi = 0; mi < 2; ++mi)
        #pragma unroll
        for (int nt = 0; nt < 4; ++nt) { acc[mi][nt].x=0.f; acc[mi][nt].y=0.f; acc[mi][nt].z=0.f; acc[mi][nt].w=0.f; }

    __syncthreads();   // ys ready

    #pragma unroll
    for (int ds = 0; ds < 4; ++ds) {
        const int dir = ds>>1, buf = ds&1;
        // A-frags (aT rows q for this wave) -> regs; in flight during PT
        bf8 ar[2][4];
        #pragma unroll
        for (int mi = 0; mi < 2; ++mi) {
            const int qt = 2*w + mi;
            #pragma unroll
            for (int ks = 0; ks < 4; ++ks) {
                const bool skip = (dir==0) ? (ks*32+31 < qt*16) : (ks*32 > qt*16+15);
                if (!skip)
                    ar[mi][ks] = *(const bf8*)&aT[(size_t)(n*4+ds)*16384
                                                  + (qt*16+lr)*128 + ks*32 + lq*8];
            }
        }
        // PT: rows o = w*16+lr (wave-private; no barrier needed for pt write)
        {
            const bf8 b0 = wr[ds][0], b1 = wr[ds][1];
            #pragma unroll
            for (int tt = 0; tt < 8; ++tt) {
                f4 p = {0.f,0.f,0.f,0.f};
                const bf8 a0 = *(const bf8*)&ys[tt*16+lr][lq*8];
                const bf8 a1 = *(const bf8*)&ys[tt*16+lr][32+lq*8];
                p = MFMA(a0,b0,p); p = MFMA(a1,b1,p);
                *(s4*)&pt[buf][w*16+lr][tt*16+lq*4] = packf4(p.x,p.y,p.z,p.w);
            }
        }
        __syncthreads();   // pt[buf] visible to all waves; ar loads drained
        // U accumulate: A = ar (q rows), B = pt[buf] (o rows)
        #pragma unroll
        for (int ks = 0; ks < 4; ++ks) {
            const bool skip0 = (dir==0) ? (ks*32+31 < (2*w)*16)   : (ks*32 > (2*w)*16+15);
            const bool skip1 = (dir==0) ? (ks*32+31 < (2*w+1)*16) : (ks*32 > (2*w+1)*16+15);
            if (skip0 && skip1) continue;
            bf8 bfr[4];
            #pragma unroll
            for (int nt = 0; nt < 4; ++nt)
                bfr[nt] = *(const bf8*)&pt[buf][nt*16+lr][ks*32+lq*8];
            if (!skip0) {
                #pragma unroll
                for (int nt = 0; nt < 4; ++nt)
                    acc[0][nt] = MFMA(ar[0][ks], bfr[nt], acc[0][nt]);
            }
            if (!skip1) {
                #pragma unroll
                for (int nt = 0; nt < 4; ++nt)
                    acc[1][nt] = MFMA(ar[1][ks], bfr[nt], acc[1][nt]);
            }
        }
        // no second barrier: next ds writes pt[buf^1]; pt[buf] reads are done
        // by every wave before the NEXT barrier, which precedes any overwrite.
    }
    // write U[q][v][o]: lane holds q = (2w+mi)*16+lq*4+j, o = nt*16+lr
    #pragma unroll
    for (int mi = 0; mi < 2; ++mi) {
        #pragma unroll
        for (int j = 0; j < 4; ++j) {
            const int q = (2*w+mi)*16 + lq*4 + j;
            short* ub = &U[((size_t)(n*128+q)*25 + v)*64 + lr];
            ub[0]  = f2bs(acc[mi][0][j]);
            ub[16] = f2bs(acc[mi][1][j]);
            ub[32] = f2bs(acc[mi][2][j]);
            ub[48] = f2bs(acc[mi][3][j]);
        }
    }
}

// temporal ff block: z1 = lrelu(y + u*sc1+sh1); Y = lrelu(y + BN(Wff@z1)) in-place
__global__ __launch_bounds__(256) void k_temporal(
    const short* __restrict__ U, short* __restrict__ Y, const short* __restrict__ wb,
    const float* __restrict__ b_out, const float* __restrict__ bn_out,
    const float* __restrict__ b_ff,  const float* __restrict__ bn_ff)
{
    const int n = blockIdx.x >> 5, qc = blockIdx.x & 31, q0 = qc*4;
    const int tid = threadIdx.x, w = tid>>6, lane = tid&63, lr = lane&15, lq = lane>>4;
    __shared__ short zs[112][72];
    __shared__ short z1[112][72];
    __shared__ short zout[112][72];
    __shared__ short wf[64][72];
    __shared__ float sc1s[64], sh1s[64], sc2s[64], sh2s[64];
    if (tid < 64) {
        float g=bn_out[tid], bb=bn_out[64+tid], m=bn_out[128+tid], vv=bn_out[192+tid];
        float inv = g*rsqrtf(vv+BN_EPS);
        sc1s[tid]=inv; sh1s[tid]=(b_out[tid]-m)*inv+bb;
        g=bn_ff[tid]; bb=bn_ff[64+tid]; m=bn_ff[128+tid]; vv=bn_ff[192+tid];
        inv = g*rsqrtf(vv+BN_EPS);
        sc2s[tid]=inv; sh2s[tid]=(b_ff[tid]-m)*inv+bb;
    }
    for (int i = tid; i < 64*8; i += 256) {
        const int o = i>>3, seg = i&7;
        *(bf8*)&wf[o][seg*8] = *(const bf8*)&wb[47104 + o*64 + seg*8];
    }
    __syncthreads();
    for (int i = tid; i < 112*8; i += 256) {
        const int row = i>>3, seg = i&7;
        bf8 yv = {0,0,0,0,0,0,0,0}, zv = yv;
        if (row < 100) {
            const int q = q0 + row/25, v = row%25;
            yv = *(const bf8*)&Y[((size_t)n*3200 + q*25 + v)*64 + seg*8];
            const bf8 uv = *(const bf8*)&U[((size_t)(n*128+q)*25 + v)*64 + seg*8];
            #pragma unroll
            for (int j = 0; j < 8; ++j) {
                const int o = seg*8+j;
                zv[j] = f2bs(lrelu(b2f(yv[j]) + b2f(uv[j])*sc1s[o] + sh1s[o]));
            }
        }
        *(bf8*)&zs[row][seg*8] = yv;
        *(bf8*)&z1[row][seg*8] = zv;
    }
    __syncthreads();
    const bf8 a0 = *(const bf8*)&wf[w*16+lr][lq*8];
    const bf8 a1 = *(const bf8*)&wf[w*16+lr][32+lq*8];
    for (int nt = 0; nt < 7; ++nt) {
        f4 acc = {0.f,0.f,0.f,0.f};
        const bf8 b0 = *(const bf8*)&z1[nt*16+lr][lq*8];
        const bf8 b1 = *(const bf8*)&z1[nt*16+lr][32+lq*8];
        acc = MFMA(a0,b0,acc); acc = MFMA(a1,b1,acc);
        const int px = nt*16+lr, o0 = w*16+lq*4;
        const s4 yr = *(const s4*)&zs[px][o0];
        const float r0 = lrelu(acc.x*sc2s[o0  ]+sh2s[o0  ]+b2f(yr.x));
        const float r1 = lrelu(acc.y*sc2s[o0+1]+sh2s[o0+1]+b2f(yr.y));
        const float r2 = lrelu(acc.z*sc2s[o0+2]+sh2s[o0+2]+b2f(yr.z));
        const float r3 = lrelu(acc.w*sc2s[o0+3]+sh2s[o0+3]+b2f(yr.w));
        *(s4*)&zout[px][o0] = packf4(r0,r1,r2,r3);
    }
    __syncthreads();
    for (int i = tid; i < 100*8; i += 256) {
        const int row = i>>3, seg = i&7;
        *(bf8*)&Y[((size_t)n*3200 + q0*25 + row)*64 + seg*8] = *(const bf8*)&zout[row][seg*8];
    }
}

// ---------------------------------------------------------------------------
// tcn v3: weights in regs; bfr hoisted per nn; 8 interleaved accumulators;
// direct global stores from MFMA D-layout (no yout LDS round-trip).
// ---------------------------------------------------------------------------
__global__ __launch_bounds__(256, 2) void k_tcn(
    const short* __restrict__ Y, const short* __restrict__ wb,
    const float* __restrict__ b, const float* __restrict__ bn,
    float* __restrict__ out)
{
    const int n = blockIdx.x >> 5, tc = (blockIdx.x >> 1) & 15, oh = blockIdx.x & 1;
    const int t0 = tc*8;
    const int tid = threadIdx.x, w = tid>>6, lane = tid&63, lr = lane&15, lq = lane>>4;
    __shared__ short zs[352][72];
    __shared__ float scs[32], shs[32];

    // weights -> registers (issued first; overlap LDS staging below)
    bf8 af[2][14];
    #pragma unroll
    for (int mt = 0; mt < 2; ++mt)
        #pragma unroll
        for (int st = 0; st < 14; ++st)
            af[mt][st] = *(const bf8*)&wb[51200 + (oh*32 + mt*16 + lr)*448 + st*32 + lq*8];

    if (tid < 32) {
        const int o = oh*32 + tid;
        const float g=bn[o], bb=bn[64+o], m=bn[128+o], vv=bn[192+o];
        const float inv = g*rsqrtf(vv+BN_EPS);
        scs[tid]=inv; shs[tid]=(b[o]-m)*inv+bb;
    }
    for (int i = tid; i < 352*8; i += 256) {
        const int row = i>>3, seg = i&7;
        bf8 val = {0,0,0,0,0,0,0,0};
        if (row < 350) {
            const int tlp = row/25, v = row%25, t = t0 - 3 + tlp;
            if (t >= 0 && t < 128)
                val = *(const bf8*)&Y[((size_t)n*3200 + t*25 + v)*64 + seg*8];
        }
        *(bf8*)&zs[row][seg*8] = val;
    }
    __syncthreads();
    for (int nn = 0; nn < 4; ++nn) {
        const int nt = w + nn*4;
        if (nt >= 13) break;
        // pixel fragments for this nt, shared by both mt
        bf8 bfr[14];
        #pragma unroll
        for (int st = 0; st < 14; ++st)
            bfr[st] = *(const bf8*)&zs[nt*16 + lr + (st>>1)*25][(st&1)*32 + lq*8];
        // 28 MFMA, 8 accumulators interleaved
        f4 ac[2][4];
        #pragma unroll
        for (int m2 = 0; m2 < 2; ++m2)
            #pragma unroll
            for (int j = 0; j < 4; ++j) { ac[m2][j].x=0.f; ac[m2][j].y=0.f; ac[m2][j].z=0.f; ac[m2][j].w=0.f; }
        #pragma unroll
        for (int st = 0; st < 14; ++st) {
            ac[0][st&3] = MFMA(af[0][st], bfr[st], ac[0][st&3]);
            ac[1][st&3] = MFMA(af[1][st], bfr[st], ac[1][st&3]);
        }
        const int px = nt*16+lr;
        if (px < 200) {
            #pragma unroll
            for (int mt = 0; mt < 2; ++mt) {
                const float ax = ac[mt][0].x+ac[mt][1].x+ac[mt][2].x+ac[mt][3].x;
                const float ay = ac[mt][0].y+ac[mt][1].y+ac[mt][2].y+ac[mt][3].y;
                const float az = ac[mt][0].z+ac[mt][1].z+ac[mt][2].z+ac[mt][3].z;
                const float aw = ac[mt][0].w+ac[mt][1].w+ac[mt][2].w+ac[mt][3].w;
                const int o0l = mt*16+lq*4;
                const s4 zr = *(const s4*)&zs[px+75][oh*32+o0l];
                float* ob = out + (size_t)n*204800 + (size_t)(oh*32+o0l)*3200 + t0*25 + px;
                ob[0]    = lrelu(ax*scs[o0l  ]+shs[o0l  ]+b2f(zr.x));
                ob[3200] = lrelu(ay*scs[o0l+1]+shs[o0l+1]+b2f(zr.y));
                ob[6400] = lrelu(az*scs[o0l+2]+shs[o0l+2]+b2f(zr.z));
                ob[9600] = lrelu(aw*scs[o0l+3]+shs[o0l+3]+b2f(zr.w));
            }
        }
    }
}

// ---------------------------------------------------------------------------
extern "C" void kernel_launch(void* const* d_in, const int* in_sizes, int n_in,
                              void* d_out, int out_size, void* d_ws, size_t ws_size,
                              hipStream_t stream) {
    const float* x        = (const float*)d_in[0];
    const float* w_in_s   = (const float*)d_in[1];
    const float* b_in_s   = (const float*)d_in[2];
    const float* alphas   = (const float*)d_in[3];
    const float* att0s    = (const float*)d_in[4];
    const float* w_out_s  = (const float*)d_in[5];
    const float* b_out_s  = (const float*)d_in[6];
    const float* bn_out_s = (const float*)d_in[7];
    const float* w_ff_s   = (const float*)d_in[8];
    const float* b_ff_s   = (const float*)d_in[9];
    const float* bn_ff_s  = (const float*)d_in[10];
    const float* w_in_t   = (const float*)d_in[11];
    const float* b_in_t   = (const float*)d_in[12];
    const float* alphat_f = (const float*)d_in[13];
    const float* alphat_b = (const float*)d_in[14];
    const float* w_out_t  = (const float*)d_in[15];
    const float* b_out_t  = (const float*)d_in[16];
    const float* bn_out_t = (const float*)d_in[17];
    const float* w_ff_t   = (const float*)d_in[18];
    const float* b_ff_t   = (const float*)d_in[19];
    const float* bn_ff_t  = (const float*)d_in[20];
    const float* w_tcn    = (const float*)d_in[21];
    const float* b_tcn    = (const float*)d_in[22];
    const float* bn_tcn   = (const float*)d_in[23];
    float* out = (float*)d_out;
    char* ws = (char*)d_ws;

    short* wb    = (short*)(ws + 0);
    short* attnB = (short*)(ws + 4102144);
    short* Y     = (short*)(ws + 4888576);
    short* aT    = (short*)(ws + 57317376);
    short* XB    = (short*)(ws + 74094592);           // phase 1
    short* QKT   = (short*)(ws + 74094592);           // phase 2 (XB dead)
    short* U     = (short*)(ws + 74094592 + 52428800);

    k_prep<<<64, 256, 0, stream>>>(w_in_s, w_out_s, w_ff_s, w_in_t, w_out_t, w_ff_t, w_tcn, wb);
    k_x2b<<<2048, 256, 0, stream>>>(x, XB);
    k_attn_s<<<NN * 3, 256, 0, stream>>>(XB, wb, b_in_s, alphas, att0s, attnB);
    k_spatial<<<4096, 256, 0, stream>>>(XB, attnB, wb, b_out_s, bn_out_s, b_ff_s, bn_ff_s, Y);
    k_qkt<<<4096, 256, 0, stream>>>(Y, wb, b_in_t, QKT);
    k_score_t<<<512, 256, 0, stream>>>(QKT, alphat_f, alphat_b, aT);
    k_tagg<<<NN * 25, 256, 0, stream>>>(Y, wb, aT, U);
    k_temporal<<<4096, 256, 0, stream>>>(U, Y, wb, b_out_t, bn_out_t, b_ff_t, bn_ff_t);
    k_tcn<<<4096, 256, 0, stream>>>(Y, wb, b_tcn, bn_tcn, out);
}